// Round 7
// baseline (397.942 us; speedup 1.0000x reference)
//
#include <hip/hip_runtime.h>
#include <math.h>

#define NEG_SLOPE 0.2f
#define BN_EPS 1e-5f

typedef __attribute__((ext_vector_type(8))) short bf16x8;
typedef __attribute__((ext_vector_type(4))) float f32x4;
typedef __attribute__((ext_vector_type(8))) unsigned short us8;

// ---------- helpers ----------

__device__ __forceinline__ void edge_sd(const int* __restrict__ ei, int E, int eid, int& s, int& d) {
    if (eid < E) { s = ei[eid]; d = ei[E + eid]; }
    else         { s = d = eid - E; }   // self-loops appended after the E real edges
}

__device__ __forceinline__ float lrelu(float v) { return v > 0.f ? v : NEG_SLOPE * v; }

// round-to-nearest-even fp32 -> bf16 bits
__device__ __forceinline__ unsigned short f2bf(float f) {
    unsigned u = __float_as_uint(f);
    u += 0x7fffu + ((u >> 16) & 1u);
    return (unsigned short)(u >> 16);
}

// ---------- W pre-pass: Wt[n][k] = bf16(W[k][n]) for both layers ----------
__global__ void wtrans_kernel(const float* __restrict__ W0, const float* __restrict__ W1,
                              unsigned short* __restrict__ Wt0, unsigned short* __restrict__ Wt1) {
    int idx = blockIdx.x * 256 + threadIdx.x;       // 0..32767
    const float* W = (idx < 16384) ? W0 : W1;
    unsigned short* Wt = (idx < 16384) ? Wt0 : Wt1;
    int i = idx & 16383;
    int k = i >> 7, n = i & 127;
    Wt[n * 128 + k] = f2bf(W[k * 128 + n]);
}

// ---------- MFMA GEMM + fused attention logits ----------
// Hbf[N,128] = bf16( act(X) @ W ), a_src/a_dst[N,8] from fp32 accumulators.
// act = BN+ELU when bnmu != nullptr (layer 1), identity otherwise.
// Tile: 64 rows/block (4 waves x 16 rows), full 128 cols; col-tile c == head c.
__global__ __launch_bounds__(256) void gemm_att_kernel(const float* __restrict__ X,
                                                       const unsigned short* __restrict__ Wt,
                                                       unsigned short* __restrict__ Hbf,
                                                       float* __restrict__ a_src,
                                                       float* __restrict__ a_dst,
                                                       const float* __restrict__ att_s,
                                                       const float* __restrict__ att_d,
                                                       const float* __restrict__ bnmu,
                                                       const float* __restrict__ bnrs,
                                                       const float* __restrict__ gamma,
                                                       const float* __restrict__ beta,
                                                       int Nrows) {
    __shared__ unsigned short xs[64 * 136];   // 64 rows x 128 bf16, row pad +8 (16B-aligned rows)
    int bm = blockIdx.x * 64;
    int tid = threadIdx.x;

    // stage X tile as bf16 (optionally BN+ELU first)
    for (int i = tid; i < 64 * 16; i += 256) {
        int row = i >> 4;
        int c8 = (i & 15) * 8;
        int grow = bm + row;
        float v[8];
        if (grow < Nrows) {
            float4 v0 = *(const float4*)(X + (size_t)grow * 128 + c8);
            float4 v1 = *(const float4*)(X + (size_t)grow * 128 + c8 + 4);
            v[0] = v0.x; v[1] = v0.y; v[2] = v0.z; v[3] = v0.w;
            v[4] = v1.x; v[5] = v1.y; v[6] = v1.z; v[7] = v1.w;
        } else {
#pragma unroll
            for (int j = 0; j < 8; j++) v[j] = 0.f;
        }
        if (bnmu != nullptr) {
#pragma unroll
            for (int j = 0; j < 8; j++) {
                int c = c8 + j;
                float t = (v[j] - bnmu[c]) * bnrs[c] * gamma[c] + beta[c];
                v[j] = t > 0.f ? t : expm1f(t);
            }
        }
        us8 p;
#pragma unroll
        for (int j = 0; j < 8; j++) p[j] = f2bf(v[j]);
        *(us8*)(xs + row * 136 + c8) = p;
    }
    __syncthreads();

    int w = tid >> 6, lane = tid & 63;
    int m16 = lane & 15;     // A row-in-tile / B col-in-tile / C col
    int quad = lane >> 4;    // 0..3

    f32x4 acc[8];
#pragma unroll
    for (int c = 0; c < 8; c++) acc[c] = (f32x4){0.f, 0.f, 0.f, 0.f};

    const unsigned short* xrow = xs + (w * 16 + m16) * 136 + quad * 8;
#pragma unroll
    for (int ks = 0; ks < 4; ks++) {
        bf16x8 a = *(const bf16x8*)(xrow + ks * 32);
#pragma unroll
        for (int c = 0; c < 8; c++) {
            bf16x8 b = *(const bf16x8*)(Wt + (c * 16 + m16) * 128 + ks * 32 + quad * 8);
            acc[c] = __builtin_amdgcn_mfma_f32_16x16x32_bf16(a, b, acc[c], 0, 0, 0);
        }
    }

    // epilogue: bf16 store + per-head att logits (fp32, quad-wide xor reduce)
#pragma unroll
    for (int c = 0; c < 8; c++) {
        float asw = att_s[c * 16 + m16];
        float adw = att_d[c * 16 + m16];
#pragma unroll
        for (int r = 0; r < 4; r++) {
            int row = bm + w * 16 + quad * 4 + r;
            float hv = acc[c][r];
            float p = hv * asw;
            float q = hv * adw;
#pragma unroll
            for (int off = 1; off < 16; off <<= 1) {
                p += __shfl_xor(p, off);
                q += __shfl_xor(q, off);
            }
            if (row < Nrows) {
                Hbf[(size_t)row * 128 + c * 16 + m16] = f2bf(hv);
                if (m16 == 0) {
                    a_src[row * 8 + c] = p;
                    a_dst[row * 8 + c] = q;
                }
            }
        }
    }
}

// ---------- CSR build: histogram of dst + within-bucket rank (atomic return value) ----------
__global__ void hist_kernel(const int* __restrict__ ei, int E, int Etot,
                            int* __restrict__ counts, int* __restrict__ rank) {
    int eid = blockIdx.x * 256 + threadIdx.x;
    if (eid >= Etot) return;
    int s, d;
    edge_sd(ei, E, eid, s, d);
    rank[eid] = atomicAdd(&counts[d], 1);
}

// ---------- CSR build: parallel 3-stage exclusive scan ----------
__global__ __launch_bounds__(256) void chunksum_kernel(const int* __restrict__ counts,
                                                       int* __restrict__ csum, int N) {
    __shared__ int red[256];
    int base = blockIdx.x * 1024;
    int s = 0;
    for (int i = threadIdx.x; i < 1024; i += 256) {
        int idx = base + i;
        s += (idx < N) ? counts[idx] : 0;
    }
    red[threadIdx.x] = s;
    __syncthreads();
#pragma unroll
    for (int st = 128; st > 0; st >>= 1) {
        if (threadIdx.x < st) red[threadIdx.x] += red[threadIdx.x + st];
        __syncthreads();
    }
    if (threadIdx.x == 0) csum[blockIdx.x] = red[0];
}

__global__ void chunkscan_kernel(int* __restrict__ csum, int nchunk) {
    int lane = threadIdx.x;
    int v = (lane < nchunk) ? csum[lane] : 0;
    int incl = v;
#pragma unroll
    for (int off = 1; off < 64; off <<= 1) {
        int t = __shfl_up(incl, off);
        if (lane >= off) incl += t;
    }
    if (lane < nchunk) csum[lane] = incl - v;
}

__global__ __launch_bounds__(1024) void scanfinal_kernel(const int* __restrict__ counts,
                                                         const int* __restrict__ csum,
                                                         int* __restrict__ rowptr, int N) {
    __shared__ int wsum[16], woff_s[16];
    int tid = threadIdx.x, lane = tid & 63, wid = tid >> 6;
    int idx = blockIdx.x * 1024 + tid;
    int v = (idx < N) ? counts[idx] : 0;
    int incl = v;
#pragma unroll
    for (int off = 1; off < 64; off <<= 1) {
        int t = __shfl_up(incl, off);
        if (lane >= off) incl += t;
    }
    if (lane == 63) wsum[wid] = incl;
    __syncthreads();
    if (wid == 0 && lane < 16) {
        int w = wsum[lane], iw = w;
#pragma unroll
        for (int off = 1; off < 16; off <<= 1) {
            int t = __shfl_up(iw, off);
            if (lane >= off) iw += t;
        }
        woff_s[lane] = iw - w;
    }
    __syncthreads();
    if (idx < N) rowptr[idx + 1] = csum[blockIdx.x] + woff_s[wid] + incl;
    if (blockIdx.x == 0 && tid == 0) rowptr[0] = 0;
}

// ---------- CSR build: scatter src ids (NO atomics; rank precomputed in hist) ----------
__global__ void scatter_kernel(const int* __restrict__ ei, int E, int Etot,
                               const int* __restrict__ rowptr, const int* __restrict__ rank,
                               unsigned short* __restrict__ ssrc) {
    int eid = blockIdx.x * 256 + threadIdx.x;
    if (eid >= Etot) return;
    int s, d;
    edge_sd(ei, E, eid, s, d);
    ssrc[rowptr[d] + rank[eid]] = (unsigned short)s;
}

// ---------- fused softmax + aggregation: one wave per dst, 8 edges per iteration ----------
template <bool MEAN>
__global__ __launch_bounds__(256) void agg_kernel(const int* __restrict__ rowptr,
                                                  const unsigned short* __restrict__ ssrc,
                                                  const float* __restrict__ a_src,
                                                  const float* __restrict__ a_dst,
                                                  const unsigned short* __restrict__ Hbf,
                                                  float* __restrict__ outbuf, int N) {
    int wid = threadIdx.x >> 6;
    int dst = blockIdx.x * 4 + wid;
    if (dst >= N) return;
    int lane = threadIdx.x & 63;
    int j  = lane >> 3;      // edge slot 0..7 (exp phase)
    int hj = lane & 7;       // head (exp phase)
    int hf = lane >> 3;      // head owning this lane's feature pair (f/16)
    int f  = lane * 2;       // features f, f+1
    int start = rowptr[dst], end = rowptr[dst + 1];
    float adst = a_dst[dst * 8 + hj];

    float acc0 = 0.f, acc1 = 0.f, denl = 0.f;
    for (int base = start; base < end; base += 8) {
        int i = base + j;
        int s = (i < end) ? (int)ssrc[i] : -1;
        float w = 0.f;
        if (s >= 0) w = __expf(lrelu(a_src[s * 8 + hj] + adst));
        denl += w;

        int   sA[8];
        float wA[8];
        unsigned uA[8];
#pragma unroll
        for (int j2 = 0; j2 < 8; j2++) {
            sA[j2] = __shfl(s, j2 * 8);          // uniform lane -> readlane (SGPR)
            wA[j2] = __shfl(w, j2 * 8 + hf);     // per-lane head -> bpermute
        }
#pragma unroll
        for (int j2 = 0; j2 < 8; j2++)
            uA[j2] = (sA[j2] >= 0) ? *(const unsigned*)(Hbf + (size_t)sA[j2] * 128 + f) : 0u;
#pragma unroll
        for (int j2 = 0; j2 < 8; j2++) {
            acc0 += wA[j2] * __uint_as_float(uA[j2] << 16);
            acc1 += wA[j2] * __uint_as_float(uA[j2] & 0xffff0000u);
        }
    }
#pragma unroll
    for (int off = 8; off < 64; off <<= 1) denl += __shfl_xor(denl, off);
    float den = __shfl(denl, hf);
    float inv = 1.f / (den + 1e-16f);
    if (!MEAN) {
        *(float2*)(outbuf + (size_t)dst * 128 + f) = make_float2(acc0 * inv, acc1 * inv);
    } else {
        float r0 = acc0 * inv, r1 = acc1 * inv;
#pragma unroll
        for (int off = 8; off < 64; off <<= 1) {
            r0 += __shfl_xor(r0, off);
            r1 += __shfl_xor(r1, off);
        }
        if (lane < 8)
            *(float2*)(outbuf + (size_t)dst * 16 + lane * 2) =
                make_float2(r0 * 0.125f, r1 * 0.125f);
    }
}

// ---------- batch-norm stats: two-stage deterministic reduction (NO atomics) ----------
template <int C>
__global__ __launch_bounds__(256) void stats_part_kernel(const float* __restrict__ X, int Nrows,
                                                         float* __restrict__ partial,
                                                         int rows_per_block) {
    constexpr int GSZ = 256 / C;
    __shared__ float ls[256], lq[256];
    int c = threadIdx.x % C;
    int g = threadIdx.x / C;
    long base = (long)blockIdx.x * rows_per_block;
    long endr = base + rows_per_block;
    if (endr > Nrows) endr = Nrows;
    float s = 0.f, q = 0.f;
    for (long r = base + g; r < endr; r += GSZ) {
        float v = X[r * C + c];
        s += v;
        q += v * v;
    }
    ls[threadIdx.x] = s;
    lq[threadIdx.x] = q;
    __syncthreads();
#pragma unroll
    for (int st = GSZ / 2; st > 0; st >>= 1) {
        if (g < st) {
            ls[threadIdx.x] += ls[threadIdx.x + st * C];
            lq[threadIdx.x] += lq[threadIdx.x + st * C];
        }
        __syncthreads();
    }
    if (g == 0) {
        partial[(size_t)blockIdx.x * (2 * C) + c] = ls[c];
        partial[(size_t)blockIdx.x * (2 * C) + C + c] = lq[c];
    }
}

template <int C>
__global__ __launch_bounds__(1024) void stats_final_kernel(const float* __restrict__ partial,
                                                           int nblk, float invN,
                                                           float* __restrict__ mu,
                                                           float* __restrict__ rsig) {
    constexpr int G = 1024 / C;
    __shared__ float ls[1024], lq[1024];
    int c = threadIdx.x % C;
    int g = threadIdx.x / C;
    float s = 0.f, q = 0.f;
    for (int b = g; b < nblk; b += G) {
        s += partial[(size_t)b * (2 * C) + c];
        q += partial[(size_t)b * (2 * C) + C + c];
    }
    ls[threadIdx.x] = s;
    lq[threadIdx.x] = q;
    __syncthreads();
#pragma unroll
    for (int st = G / 2; st > 0; st >>= 1) {
        if (g < st) {
            ls[threadIdx.x] += ls[threadIdx.x + st * C];
            lq[threadIdx.x] += lq[threadIdx.x + st * C];
        }
        __syncthreads();
    }
    if (g == 0) {
        float m_ = ls[c] * invN;
        float v = lq[c] * invN - m_ * m_;
        mu[c] = m_;
        rsig[c] = rsqrtf(v + BN_EPS);
    }
}

// ---------- final: BN(16) + logits = v @ Wc + bc ----------
__global__ void final_kernel(const float* __restrict__ out1,
                             const float* __restrict__ mu, const float* __restrict__ rsig,
                             const float* __restrict__ gamma, const float* __restrict__ beta,
                             const float* __restrict__ Wc, const float* __restrict__ bc,
                             float* __restrict__ out, int N) {
    int n = blockIdx.x * 256 + threadIdx.x;
    if (n >= N) return;
    float l0 = bc[0], l1 = bc[1];
#pragma unroll
    for (int c = 0; c < 16; c++) {
        float v = (out1[(size_t)n * 16 + c] - mu[c]) * rsig[c] * gamma[c] + beta[c];
        l0 += v * Wc[c * 2 + 0];
        l1 += v * Wc[c * 2 + 1];
    }
    out[(size_t)n * 2 + 0] = l0;
    out[(size_t)n * 2 + 1] = l1;
}

// ---------- launcher ----------
extern "C" void kernel_launch(void* const* d_in, const int* in_sizes, int n_in,
                              void* d_out, int out_size, void* d_ws, size_t ws_size,
                              hipStream_t stream) {
    const float* x   = (const float*)d_in[0];
    const int*   ei  = (const int*)d_in[1];
    const float* W0  = (const float*)d_in[2];
    const float* as0 = (const float*)d_in[3];
    const float* ad0 = (const float*)d_in[4];
    // d_in[5] = b0: cancelled exactly by the following batch-norm's mean subtraction
    const float* g0  = (const float*)d_in[6];
    const float* be0 = (const float*)d_in[7];
    const float* W1  = (const float*)d_in[8];
    const float* as1 = (const float*)d_in[9];
    const float* ad1 = (const float*)d_in[10];
    // d_in[11] = b1: cancelled by BN as well
    const float* g1  = (const float*)d_in[12];
    const float* be1 = (const float*)d_in[13];
    const float* Wc  = (const float*)d_in[14];
    const float* bc  = (const float*)d_in[15];
    float* out = (float*)d_out;

    int N = in_sizes[0] / 128;
    int E = in_sizes[1] / 2;
    int Etot = E + N;

    // workspace layout
    char* ws = (char*)d_ws;
    size_t off = 0;
    auto walloc = [&](size_t bytes) -> void* {
        void* p = ws + off;
        off += (bytes + 255) & ~(size_t)255;
        return p;
    };
    float*          B       = (float*)walloc((size_t)N * 128 * 4);
    unsigned short* Hbf     = (unsigned short*)walloc((size_t)N * 128 * 2);
    unsigned short* Wt0     = (unsigned short*)walloc(128 * 128 * 2);
    unsigned short* Wt1     = (unsigned short*)walloc(128 * 128 * 2);
    float*          a_src   = (float*)walloc((size_t)N * 8 * 4);
    float*          a_dst   = (float*)walloc((size_t)N * 8 * 4);
    float*          out1    = (float*)walloc((size_t)N * 16 * 4);
    int*            counts  = (int*)walloc((size_t)N * 4);
    int*            rowptr  = (int*)walloc((size_t)(N + 1) * 4);
    int*            rank    = (int*)walloc((size_t)Etot * 4);
    int*            csum    = (int*)walloc(64 * 4);
    unsigned short* ssrc    = (unsigned short*)walloc((size_t)Etot * 2);
    float*          partial = (float*)walloc((size_t)256 * 256 * 4);   // [256 blocks][2*128]
    float*          stats   = (float*)walloc(2 * 128 * 4);
    float* mu = stats, * rsig = stats + 128;

    dim3 b256(256);
    int gN64    = (N + 63) / 64;
    int gE      = (Etot + 255) / 256;
    int gAgg    = (N + 3) / 4;
    int nchunk  = (N + 1023) / 1024;
    const int SBLK = 256;
    int rpb = (N + SBLK - 1) / SBLK;

    // ---- CSR build (once; same graph for both layers) ----
    hipMemsetAsync(counts, 0, (size_t)N * 4, stream);
    hist_kernel<<<gE, b256, 0, stream>>>(ei, E, Etot, counts, rank);
    chunksum_kernel<<<nchunk, b256, 0, stream>>>(counts, csum, N);
    chunkscan_kernel<<<1, 64, 0, stream>>>(csum, nchunk);
    scanfinal_kernel<<<nchunk, 1024, 0, stream>>>(counts, csum, rowptr, N);
    scatter_kernel<<<gE, b256, 0, stream>>>(ei, E, Etot, rowptr, rank, ssrc);

    // ---- W transpose + bf16 convert (both layers) ----
    wtrans_kernel<<<128, b256, 0, stream>>>(W0, W1, Wt0, Wt1);

    // ---- layer 0 ----
    gemm_att_kernel<<<gN64, b256, 0, stream>>>(x, Wt0, Hbf, a_src, a_dst, as0, ad0,
                                               nullptr, nullptr, nullptr, nullptr, N);
    agg_kernel<false><<<gAgg, b256, 0, stream>>>(rowptr, ssrc, a_src, a_dst, Hbf, B, N); // B = agg0
    stats_part_kernel<128><<<SBLK, b256, 0, stream>>>(B, N, partial, rpb);
    stats_final_kernel<128><<<1, 1024, 0, stream>>>(partial, SBLK, 1.0f / N, mu, rsig);

    // ---- layer 1 (BN+ELU fused into gemm X staging) ----
    gemm_att_kernel<<<gN64, b256, 0, stream>>>(B, Wt1, Hbf, a_src, a_dst, as1, ad1,
                                               mu, rsig, g0, be0, N);
    agg_kernel<true><<<gAgg, b256, 0, stream>>>(rowptr, ssrc, a_src, a_dst, Hbf, out1, N);
    stats_part_kernel<16><<<SBLK, b256, 0, stream>>>(out1, N, partial, rpb);
    stats_final_kernel<16><<<1, 1024, 0, stream>>>(partial, SBLK, 1.0f / N, mu, rsig);
    final_kernel<<<(N + 255) / 256, b256, 0, stream>>>(out1, mu, rsig, g1, be1, Wc, bc, out, N);
}

// Round 8
// 383.216 us; speedup vs baseline: 1.0384x; 1.0384x over previous
//
#include <hip/hip_runtime.h>
#include <math.h>

#define NEG_SLOPE 0.2f
#define BN_EPS 1e-5f

typedef __attribute__((ext_vector_type(8))) short bf16x8;
typedef __attribute__((ext_vector_type(4))) float f32x4;
typedef __attribute__((ext_vector_type(8))) unsigned short us8;

// ---------- helpers ----------

__device__ __forceinline__ void edge_sd(const int* __restrict__ ei, int E, int eid, int& s, int& d) {
    if (eid < E) { s = ei[eid]; d = ei[E + eid]; }
    else         { s = d = eid - E; }   // self-loops appended after the E real edges
}

__device__ __forceinline__ float lrelu(float v) { return v > 0.f ? v : NEG_SLOPE * v; }

// round-to-nearest-even fp32 -> bf16 bits
__device__ __forceinline__ unsigned short f2bf(float f) {
    unsigned u = __float_as_uint(f);
    u += 0x7fffu + ((u >> 16) & 1u);
    return (unsigned short)(u >> 16);
}

// ---------- W' pre-pass: Wt = [W | W@att_s | W@att_d] transposed, bf16, tile-major ----------
// Layout: Wt[t*2048 + col16*128 + k], t=0..8. Tile 8: cols 0..7 = a_src proj, 8..15 = a_dst proj.
// Folding att into W makes the GEMM emit attention logits directly (no epilogue reductions).
__global__ void wtrans_kernel(const float* __restrict__ W0, const float* __restrict__ as0,
                              const float* __restrict__ ad0,
                              const float* __restrict__ W1, const float* __restrict__ as1,
                              const float* __restrict__ ad1,
                              unsigned short* __restrict__ Wt0, unsigned short* __restrict__ Wt1) {
    int idx = blockIdx.x * 256 + threadIdx.x;   // 0..36863
    const float *W, *as_, *ad_;
    unsigned short* Wt;
    int i;
    if (idx < 18432) { W = W0; as_ = as0; ad_ = ad0; Wt = Wt0; i = idx; }
    else             { W = W1; as_ = as1; ad_ = ad1; Wt = Wt1; i = idx - 18432; }
    if (i < 16384) {
        int k = i >> 7, n = i & 127;
        Wt[(n >> 4) * 2048 + (n & 15) * 128 + k] = f2bf(W[k * 128 + n]);
    } else {
        int j = i - 16384;          // 0..2047
        int k = j >> 4, hh = j & 15;
        int h = hh & 7;
        const float* av = (hh < 8) ? as_ : ad_;
        float s = 0.f;
#pragma unroll
        for (int c = 0; c < 16; c++) s += W[k * 128 + h * 16 + c] * av[h * 16 + c];
        Wt[8 * 2048 + hh * 128 + k] = f2bf(s);
    }
}

// ---------- MFMA GEMM, att logits fused via augmented W' ----------
// Hbf[N,128] = bf16( act(X) @ W ); a_src/a_dst[N,8] = act(X) @ Was/Wad (tile 8).
// act = BN+ELU when bnmu != nullptr (layer 1). Epilogue is pure stores.
__global__ __launch_bounds__(256) void gemm_att_kernel(const float* __restrict__ X,
                                                       const unsigned short* __restrict__ Wt,
                                                       unsigned short* __restrict__ Hbf,
                                                       float* __restrict__ a_src,
                                                       float* __restrict__ a_dst,
                                                       const float* __restrict__ bnmu,
                                                       const float* __restrict__ bnrs,
                                                       const float* __restrict__ gamma,
                                                       const float* __restrict__ beta,
                                                       int Nrows) {
    __shared__ unsigned short xs[64 * 136];   // 64 rows x 128 bf16, +8 pad per row
    int bm = blockIdx.x * 64;
    int tid = threadIdx.x;

    // stage X tile as bf16 (optionally BN+ELU first)
    for (int i = tid; i < 64 * 16; i += 256) {
        int row = i >> 4;
        int c8 = (i & 15) * 8;
        int grow = bm + row;
        float v[8];
        if (grow < Nrows) {
            float4 v0 = *(const float4*)(X + (size_t)grow * 128 + c8);
            float4 v1 = *(const float4*)(X + (size_t)grow * 128 + c8 + 4);
            v[0] = v0.x; v[1] = v0.y; v[2] = v0.z; v[3] = v0.w;
            v[4] = v1.x; v[5] = v1.y; v[6] = v1.z; v[7] = v1.w;
        } else {
#pragma unroll
            for (int j = 0; j < 8; j++) v[j] = 0.f;
        }
        if (bnmu != nullptr) {
#pragma unroll
            for (int j = 0; j < 8; j++) {
                int c = c8 + j;
                float t = (v[j] - bnmu[c]) * bnrs[c] * gamma[c] + beta[c];
                v[j] = t > 0.f ? t : expm1f(t);
            }
        }
        us8 p;
#pragma unroll
        for (int j = 0; j < 8; j++) p[j] = f2bf(v[j]);
        *(us8*)(xs + row * 136 + c8) = p;
    }
    __syncthreads();

    int w = tid >> 6, lane = tid & 63;
    int m16 = lane & 15;     // A row-in-tile / B col-in-tile / C col
    int quad = lane >> 4;    // 0..3

    f32x4 acc[9];
#pragma unroll
    for (int c = 0; c < 9; c++) acc[c] = (f32x4){0.f, 0.f, 0.f, 0.f};

    const unsigned short* xrow = xs + (w * 16 + m16) * 136 + quad * 8;
#pragma unroll
    for (int ks = 0; ks < 4; ks++) {
        bf16x8 a = *(const bf16x8*)(xrow + ks * 32);
#pragma unroll
        for (int c = 0; c < 9; c++) {
            bf16x8 b = *(const bf16x8*)(Wt + c * 2048 + m16 * 128 + ks * 32 + quad * 8);
            acc[c] = __builtin_amdgcn_mfma_f32_16x16x32_bf16(a, b, acc[c], 0, 0, 0);
        }
    }

    // epilogue: pure stores (C layout: col = m16, row = quad*4 + r)
    int rowb = bm + w * 16 + quad * 4;
#pragma unroll
    for (int c = 0; c < 8; c++) {
#pragma unroll
        for (int r = 0; r < 4; r++) {
            int row = rowb + r;
            if (row < Nrows)
                Hbf[(size_t)row * 128 + c * 16 + m16] = f2bf(acc[c][r]);
        }
    }
#pragma unroll
    for (int r = 0; r < 4; r++) {
        int row = rowb + r;
        if (row < Nrows) {
            if (m16 < 8) a_src[row * 8 + m16] = acc[8][r];
            else         a_dst[row * 8 + (m16 - 8)] = acc[8][r];
        }
    }
}

// ---------- CSR build: histogram of dst + within-bucket rank (atomic return value) ----------
__global__ void hist_kernel(const int* __restrict__ ei, int E, int Etot,
                            int* __restrict__ counts, int* __restrict__ rank) {
    int eid = blockIdx.x * 256 + threadIdx.x;
    if (eid >= Etot) return;
    int s, d;
    edge_sd(ei, E, eid, s, d);
    rank[eid] = atomicAdd(&counts[d], 1);
}

// ---------- CSR build: parallel 3-stage exclusive scan ----------
__global__ __launch_bounds__(256) void chunksum_kernel(const int* __restrict__ counts,
                                                       int* __restrict__ csum, int N) {
    __shared__ int red[256];
    int base = blockIdx.x * 1024;
    int s = 0;
    for (int i = threadIdx.x; i < 1024; i += 256) {
        int idx = base + i;
        s += (idx < N) ? counts[idx] : 0;
    }
    red[threadIdx.x] = s;
    __syncthreads();
#pragma unroll
    for (int st = 128; st > 0; st >>= 1) {
        if (threadIdx.x < st) red[threadIdx.x] += red[threadIdx.x + st];
        __syncthreads();
    }
    if (threadIdx.x == 0) csum[blockIdx.x] = red[0];
}

__global__ void chunkscan_kernel(int* __restrict__ csum, int nchunk) {
    int lane = threadIdx.x;
    int v = (lane < nchunk) ? csum[lane] : 0;
    int incl = v;
#pragma unroll
    for (int off = 1; off < 64; off <<= 1) {
        int t = __shfl_up(incl, off);
        if (lane >= off) incl += t;
    }
    if (lane < nchunk) csum[lane] = incl - v;
}

__global__ __launch_bounds__(1024) void scanfinal_kernel(const int* __restrict__ counts,
                                                         const int* __restrict__ csum,
                                                         int* __restrict__ rowptr, int N) {
    __shared__ int wsum[16], woff_s[16];
    int tid = threadIdx.x, lane = tid & 63, wid = tid >> 6;
    int idx = blockIdx.x * 1024 + tid;
    int v = (idx < N) ? counts[idx] : 0;
    int incl = v;
#pragma unroll
    for (int off = 1; off < 64; off <<= 1) {
        int t = __shfl_up(incl, off);
        if (lane >= off) incl += t;
    }
    if (lane == 63) wsum[wid] = incl;
    __syncthreads();
    if (wid == 0 && lane < 16) {
        int w = wsum[lane], iw = w;
#pragma unroll
        for (int off = 1; off < 16; off <<= 1) {
            int t = __shfl_up(iw, off);
            if (lane >= off) iw += t;
        }
        woff_s[lane] = iw - w;
    }
    __syncthreads();
    if (idx < N) rowptr[idx + 1] = csum[blockIdx.x] + woff_s[wid] + incl;
    if (blockIdx.x == 0 && tid == 0) rowptr[0] = 0;
}

// ---------- CSR build: scatter src ids (NO atomics; rank precomputed in hist) ----------
__global__ void scatter_kernel(const int* __restrict__ ei, int E, int Etot,
                               const int* __restrict__ rowptr, const int* __restrict__ rank,
                               unsigned short* __restrict__ ssrc) {
    int eid = blockIdx.x * 256 + threadIdx.x;
    if (eid >= Etot) return;
    int s, d;
    edge_sd(ei, E, eid, s, d);
    ssrc[rowptr[d] + rank[eid]] = (unsigned short)s;
}

// ---------- fused softmax + aggregation: one wave per dst, 8 edges per iteration ----------
template <bool MEAN>
__global__ __launch_bounds__(256) void agg_kernel(const int* __restrict__ rowptr,
                                                  const unsigned short* __restrict__ ssrc,
                                                  const float* __restrict__ a_src,
                                                  const float* __restrict__ a_dst,
                                                  const unsigned short* __restrict__ Hbf,
                                                  float* __restrict__ outbuf, int N) {
    int wid = threadIdx.x >> 6;
    int dst = blockIdx.x * 4 + wid;
    if (dst >= N) return;
    int lane = threadIdx.x & 63;
    int j  = lane >> 3;      // edge slot 0..7 (exp phase)
    int hj = lane & 7;       // head (exp phase)
    int hf = lane >> 3;      // head owning this lane's feature pair (f/16)
    int f  = lane * 2;       // features f, f+1
    int start = rowptr[dst], end = rowptr[dst + 1];
    float adst = a_dst[dst * 8 + hj];

    float acc0 = 0.f, acc1 = 0.f, denl = 0.f;
    for (int base = start; base < end; base += 8) {
        int i = base + j;
        int s = (i < end) ? (int)ssrc[i] : -1;
        float w = 0.f;
        if (s >= 0) w = __expf(lrelu(a_src[s * 8 + hj] + adst));
        denl += w;

        int   sA[8];
        float wA[8];
        unsigned uA[8];
#pragma unroll
        for (int j2 = 0; j2 < 8; j2++) {
            sA[j2] = __shfl(s, j2 * 8);          // uniform lane -> readlane (SGPR)
            wA[j2] = __shfl(w, j2 * 8 + hf);     // per-lane head -> bpermute
        }
#pragma unroll
        for (int j2 = 0; j2 < 8; j2++)
            uA[j2] = (sA[j2] >= 0) ? *(const unsigned*)(Hbf + (size_t)sA[j2] * 128 + f) : 0u;
#pragma unroll
        for (int j2 = 0; j2 < 8; j2++) {
            acc0 += wA[j2] * __uint_as_float(uA[j2] << 16);
            acc1 += wA[j2] * __uint_as_float(uA[j2] & 0xffff0000u);
        }
    }
#pragma unroll
    for (int off = 8; off < 64; off <<= 1) denl += __shfl_xor(denl, off);
    float den = __shfl(denl, hf);
    float inv = 1.f / (den + 1e-16f);
    if (!MEAN) {
        *(float2*)(outbuf + (size_t)dst * 128 + f) = make_float2(acc0 * inv, acc1 * inv);
    } else {
        float r0 = acc0 * inv, r1 = acc1 * inv;
#pragma unroll
        for (int off = 8; off < 64; off <<= 1) {
            r0 += __shfl_xor(r0, off);
            r1 += __shfl_xor(r1, off);
        }
        if (lane < 8)
            *(float2*)(outbuf + (size_t)dst * 16 + lane * 2) =
                make_float2(r0 * 0.125f, r1 * 0.125f);
    }
}

// ---------- batch-norm stats: two-stage deterministic reduction (NO atomics) ----------
template <int C>
__global__ __launch_bounds__(256) void stats_part_kernel(const float* __restrict__ X, int Nrows,
                                                         float* __restrict__ partial,
                                                         int rows_per_block) {
    constexpr int GSZ = 256 / C;
    __shared__ float ls[256], lq[256];
    int c = threadIdx.x % C;
    int g = threadIdx.x / C;
    long base = (long)blockIdx.x * rows_per_block;
    long endr = base + rows_per_block;
    if (endr > Nrows) endr = Nrows;
    float s = 0.f, q = 0.f;
    for (long r = base + g; r < endr; r += GSZ) {
        float v = X[r * C + c];
        s += v;
        q += v * v;
    }
    ls[threadIdx.x] = s;
    lq[threadIdx.x] = q;
    __syncthreads();
#pragma unroll
    for (int st = GSZ / 2; st > 0; st >>= 1) {
        if (g < st) {
            ls[threadIdx.x] += ls[threadIdx.x + st * C];
            lq[threadIdx.x] += lq[threadIdx.x + st * C];
        }
        __syncthreads();
    }
    if (g == 0) {
        partial[(size_t)blockIdx.x * (2 * C) + c] = ls[c];
        partial[(size_t)blockIdx.x * (2 * C) + C + c] = lq[c];
    }
}

template <int C>
__global__ __launch_bounds__(1024) void stats_final_kernel(const float* __restrict__ partial,
                                                           int nblk, float invN,
                                                           float* __restrict__ mu,
                                                           float* __restrict__ rsig) {
    constexpr int G = 1024 / C;
    __shared__ float ls[1024], lq[1024];
    int c = threadIdx.x % C;
    int g = threadIdx.x / C;
    float s = 0.f, q = 0.f;
    for (int b = g; b < nblk; b += G) {
        s += partial[(size_t)b * (2 * C) + c];
        q += partial[(size_t)b * (2 * C) + C + c];
    }
    ls[threadIdx.x] = s;
    lq[threadIdx.x] = q;
    __syncthreads();
#pragma unroll
    for (int st = G / 2; st > 0; st >>= 1) {
        if (g < st) {
            ls[threadIdx.x] += ls[threadIdx.x + st * C];
            lq[threadIdx.x] += lq[threadIdx.x + st * C];
        }
        __syncthreads();
    }
    if (g == 0) {
        float m_ = ls[c] * invN;
        float v = lq[c] * invN - m_ * m_;
        mu[c] = m_;
        rsig[c] = rsqrtf(v + BN_EPS);
    }
}

// ---------- final: BN(16) + logits = v @ Wc + bc ----------
__global__ void final_kernel(const float* __restrict__ out1,
                             const float* __restrict__ mu, const float* __restrict__ rsig,
                             const float* __restrict__ gamma, const float* __restrict__ beta,
                             const float* __restrict__ Wc, const float* __restrict__ bc,
                             float* __restrict__ out, int N) {
    int n = blockIdx.x * 256 + threadIdx.x;
    if (n >= N) return;
    float l0 = bc[0], l1 = bc[1];
#pragma unroll
    for (int c = 0; c < 16; c++) {
        float v = (out1[(size_t)n * 16 + c] - mu[c]) * rsig[c] * gamma[c] + beta[c];
        l0 += v * Wc[c * 2 + 0];
        l1 += v * Wc[c * 2 + 1];
    }
    out[(size_t)n * 2 + 0] = l0;
    out[(size_t)n * 2 + 1] = l1;
}

// ---------- launcher ----------
extern "C" void kernel_launch(void* const* d_in, const int* in_sizes, int n_in,
                              void* d_out, int out_size, void* d_ws, size_t ws_size,
                              hipStream_t stream) {
    const float* x   = (const float*)d_in[0];
    const int*   ei  = (const int*)d_in[1];
    const float* W0  = (const float*)d_in[2];
    const float* as0 = (const float*)d_in[3];
    const float* ad0 = (const float*)d_in[4];
    // d_in[5] = b0: cancelled exactly by the following batch-norm's mean subtraction
    const float* g0  = (const float*)d_in[6];
    const float* be0 = (const float*)d_in[7];
    const float* W1  = (const float*)d_in[8];
    const float* as1 = (const float*)d_in[9];
    const float* ad1 = (const float*)d_in[10];
    // d_in[11] = b1: cancelled by BN as well
    const float* g1  = (const float*)d_in[12];
    const float* be1 = (const float*)d_in[13];
    const float* Wc  = (const float*)d_in[14];
    const float* bc  = (const float*)d_in[15];
    float* out = (float*)d_out;

    int N = in_sizes[0] / 128;
    int E = in_sizes[1] / 2;
    int Etot = E + N;

    // workspace layout
    char* ws = (char*)d_ws;
    size_t off = 0;
    auto walloc = [&](size_t bytes) -> void* {
        void* p = ws + off;
        off += (bytes + 255) & ~(size_t)255;
        return p;
    };
    float*          B       = (float*)walloc((size_t)N * 128 * 4);
    unsigned short* Hbf     = (unsigned short*)walloc((size_t)N * 128 * 2);
    unsigned short* Wt0     = (unsigned short*)walloc(144 * 128 * 2);
    unsigned short* Wt1     = (unsigned short*)walloc(144 * 128 * 2);
    float*          a_src   = (float*)walloc((size_t)N * 8 * 4);
    float*          a_dst   = (float*)walloc((size_t)N * 8 * 4);
    float*          out1    = (float*)walloc((size_t)N * 16 * 4);
    int*            counts  = (int*)walloc((size_t)N * 4);
    int*            rowptr  = (int*)walloc((size_t)(N + 1) * 4);
    int*            rank    = (int*)walloc((size_t)Etot * 4);
    int*            csum    = (int*)walloc(64 * 4);
    unsigned short* ssrc    = (unsigned short*)walloc((size_t)Etot * 2);
    float*          partial = (float*)walloc((size_t)256 * 256 * 4);   // [256 blocks][2*128]
    float*          stats   = (float*)walloc(2 * 128 * 4);
    float* mu = stats, * rsig = stats + 128;

    dim3 b256(256);
    int gN64    = (N + 63) / 64;
    int gE      = (Etot + 255) / 256;
    int gAgg    = (N + 3) / 4;
    int nchunk  = (N + 1023) / 1024;
    const int SBLK = 256;
    int rpb = (N + SBLK - 1) / SBLK;

    // ---- CSR build (once; same graph for both layers) ----
    hipMemsetAsync(counts, 0, (size_t)N * 4, stream);
    hist_kernel<<<gE, b256, 0, stream>>>(ei, E, Etot, counts, rank);
    chunksum_kernel<<<nchunk, b256, 0, stream>>>(counts, csum, N);
    chunkscan_kernel<<<1, 64, 0, stream>>>(csum, nchunk);
    scanfinal_kernel<<<nchunk, 1024, 0, stream>>>(counts, csum, rowptr, N);
    scatter_kernel<<<gE, b256, 0, stream>>>(ei, E, Etot, rowptr, rank, ssrc);

    // ---- W' build: transpose + bf16 + folded att projections (both layers) ----
    wtrans_kernel<<<144, b256, 0, stream>>>(W0, as0, ad0, W1, as1, ad1, Wt0, Wt1);

    // ---- layer 0 ----
    gemm_att_kernel<<<gN64, b256, 0, stream>>>(x, Wt0, Hbf, a_src, a_dst,
                                               nullptr, nullptr, nullptr, nullptr, N);
    agg_kernel<false><<<gAgg, b256, 0, stream>>>(rowptr, ssrc, a_src, a_dst, Hbf, B, N); // B = agg0
    stats_part_kernel<128><<<SBLK, b256, 0, stream>>>(B, N, partial, rpb);
    stats_final_kernel<128><<<1, 1024, 0, stream>>>(partial, SBLK, 1.0f / N, mu, rsig);

    // ---- layer 1 (BN+ELU fused into gemm X staging) ----
    gemm_att_kernel<<<gN64, b256, 0, stream>>>(B, Wt1, Hbf, a_src, a_dst,
                                               mu, rsig, g0, be0, N);
    agg_kernel<true><<<gAgg, b256, 0, stream>>>(rowptr, ssrc, a_src, a_dst, Hbf, out1, N);
    stats_part_kernel<16><<<SBLK, b256, 0, stream>>>(out1, N, partial, rpb);
    stats_final_kernel<16><<<1, 1024, 0, stream>>>(partial, SBLK, 1.0f / N, mu, rsig);
    final_kernel<<<(N + 255) / 256, b256, 0, stream>>>(out1, mu, rsig, g1, be1, Wc, bc, out, N);
}

// Round 9
// 364.041 us; speedup vs baseline: 1.0931x; 1.0527x over previous
//
#include <hip/hip_runtime.h>
#include <math.h>

#define NEG_SLOPE 0.2f
#define BN_EPS 1e-5f

typedef __attribute__((ext_vector_type(8))) short bf16x8;
typedef __attribute__((ext_vector_type(4))) float f32x4;

// ---------- helpers ----------

__device__ __forceinline__ void edge_sd(const int* __restrict__ ei, int E, int eid, int& s, int& d) {
    if (eid < E) { s = ei[eid]; d = ei[E + eid]; }
    else         { s = d = eid - E; }   // self-loops appended after the E real edges
}

__device__ __forceinline__ float lrelu(float v) { return v > 0.f ? v : NEG_SLOPE * v; }

// round-to-nearest-even fp32 -> bf16 bits
__device__ __forceinline__ unsigned short f2bf(float f) {
    unsigned u = __float_as_uint(f);
    u += 0x7fffu + ((u >> 16) & 1u);
    return (unsigned short)(u >> 16);
}

// ---------- W' pre-pass: Wt = [W | W@att_s | W@att_d] transposed, bf16, tile-major ----------
// Layout: Wt[t*2048 + col16*128 + k], t=0..8. Tile 8: cols 0..7 = a_src proj, 8..15 = a_dst proj.
__global__ void wtrans_kernel(const float* __restrict__ W0, const float* __restrict__ as0,
                              const float* __restrict__ ad0,
                              const float* __restrict__ W1, const float* __restrict__ as1,
                              const float* __restrict__ ad1,
                              unsigned short* __restrict__ Wt0, unsigned short* __restrict__ Wt1) {
    int idx = blockIdx.x * 256 + threadIdx.x;   // 0..36863
    const float *W, *as_, *ad_;
    unsigned short* Wt;
    int i;
    if (idx < 18432) { W = W0; as_ = as0; ad_ = ad0; Wt = Wt0; i = idx; }
    else             { W = W1; as_ = as1; ad_ = ad1; Wt = Wt1; i = idx - 18432; }
    if (i < 16384) {
        int k = i >> 7, n = i & 127;
        Wt[(n >> 4) * 2048 + (n & 15) * 128 + k] = f2bf(W[k * 128 + n]);
    } else {
        int j = i - 16384;          // 0..2047
        int k = j >> 4, hh = j & 15;
        int h = hh & 7;
        const float* av = (hh < 8) ? as_ : ad_;
        float s = 0.f;
#pragma unroll
        for (int c = 0; c < 16; c++) s += W[k * 128 + h * 16 + c] * av[h * 16 + c];
        Wt[8 * 2048 + hh * 128 + k] = f2bf(s);
    }
}

// ---------- persistent-W MFMA GEMM, att logits fused via augmented W' ----------
// W' staged to LDS once per block; waves grid-stride over 16-row tiles with NO
// further barriers. BN+ELU folded into the per-element load path (scale/shift in LDS).
#define WCOLSTRIDE 132   // ushorts per col (pad 128->132: ds_read_b128 aliasing <=2-way)
#define WTILESZ (16 * WCOLSTRIDE)
__global__ __launch_bounds__(256, 4) void gemm_att_kernel(const float* __restrict__ X,
                                                          const unsigned short* __restrict__ Wt,
                                                          unsigned short* __restrict__ Hbf,
                                                          float* __restrict__ a_src,
                                                          float* __restrict__ a_dst,
                                                          const float* __restrict__ bnmu,
                                                          const float* __restrict__ bnrs,
                                                          const float* __restrict__ gamma,
                                                          const float* __restrict__ beta,
                                                          int Nrows) {
    __shared__ unsigned short wl[9 * WTILESZ];   // 9 col-tiles x 16 cols x 128 k (padded)
    __shared__ float ss[256];                    // scale[128], shift[128]
    int tid = threadIdx.x;

    // fold BN into scale/shift (identity when bnmu == nullptr)
    if (tid < 128) {
        float sc = 1.f, sh = 0.f;
        if (bnmu != nullptr) {
            float rg = bnrs[tid] * gamma[tid];
            sc = rg;
            sh = beta[tid] - bnmu[tid] * rg;
        }
        ss[tid] = sc;
        ss[128 + tid] = sh;
    }
    // stage W' into LDS (once per block)
    for (int i = tid; i < 9 * 16 * 16; i += 256) {   // uint4 chunks of 8 ushorts
        int c = i >> 8, rem = i & 255, col = rem >> 4, k8 = rem & 15;
        uint4 v = *(const uint4*)(Wt + c * 2048 + col * 128 + k8 * 8);
        *(uint4*)(wl + c * WTILESZ + col * WCOLSTRIDE + k8 * 8) = v;
    }
    __syncthreads();

    int w = tid >> 6, lane = tid & 63;
    int m16 = lane & 15;     // A row-in-tile (loads) / B col / C col
    int quad = lane >> 4;    // A,B k-segment (loads) / C row group
    int gw = blockIdx.x * 4 + w;
    int nw = gridDim.x * 4;
    int ntiles = (Nrows + 15) / 16;
    bool dobn = (bnmu != nullptr);
    const float* scp = ss + quad * 8;        // per-ks offset added below (quad segment)
    const float* shp = ss + 128 + quad * 8;

    for (int t = gw; t < ntiles; t += nw) {
        int rl = t * 16 + m16;
        if (rl >= Nrows) rl = Nrows - 1;
        const float* Xr = X + (size_t)rl * 128 + quad * 8;

        // issue all 8 X loads (independent, coalesced: 16 rows x 128B per instr)
        float4 u[8];
#pragma unroll
        for (int ks = 0; ks < 4; ks++) {
            u[2 * ks]     = *(const float4*)(Xr + ks * 32);
            u[2 * ks + 1] = *(const float4*)(Xr + ks * 32 + 4);
        }
        // convert (+BN+ELU for layer 1) -> 4 bf16x8 A-fragments
        bf16x8 afr[4];
#pragma unroll
        for (int ks = 0; ks < 4; ks++) {
            float vv[8] = {u[2 * ks].x, u[2 * ks].y, u[2 * ks].z, u[2 * ks].w,
                           u[2 * ks + 1].x, u[2 * ks + 1].y, u[2 * ks + 1].z, u[2 * ks + 1].w};
            if (dobn) {
#pragma unroll
                for (int j = 0; j < 8; j++) {
                    float tv = vv[j] * scp[ks * 32 + j] + shp[ks * 32 + j];
                    vv[j] = tv > 0.f ? tv : expm1f(tv);
                }
            }
            union { bf16x8 b; unsigned short s[8]; } pk;
#pragma unroll
            for (int j = 0; j < 8; j++) pk.s[j] = f2bf(vv[j]);
            afr[ks] = pk.b;
        }

        // MFMA: 9 col-tiles x 4 k-steps, B from LDS
        f32x4 acc[9];
#pragma unroll
        for (int c = 0; c < 9; c++) acc[c] = (f32x4){0.f, 0.f, 0.f, 0.f};
        const unsigned short* wb = wl + m16 * WCOLSTRIDE + quad * 8;
#pragma unroll
        for (int ks = 0; ks < 4; ks++) {
#pragma unroll
            for (int c = 0; c < 9; c++) {
                bf16x8 b = *(const bf16x8*)(wb + c * WTILESZ + ks * 32);
                acc[c] = __builtin_amdgcn_mfma_f32_16x16x32_bf16(afr[ks], b, acc[c], 0, 0, 0);
            }
        }

        // epilogue: pure stores (C layout: col = m16, row = quad*4 + r)
        int rowb = t * 16 + quad * 4;
#pragma unroll
        for (int c = 0; c < 8; c++) {
#pragma unroll
            for (int r = 0; r < 4; r++) {
                int row = rowb + r;
                if (row < Nrows)
                    Hbf[(size_t)row * 128 + c * 16 + m16] = f2bf(acc[c][r]);
            }
        }
#pragma unroll
        for (int r = 0; r < 4; r++) {
            int row = rowb + r;
            if (row < Nrows) {
                if (m16 < 8) a_src[row * 8 + m16] = acc[8][r];
                else         a_dst[row * 8 + (m16 - 8)] = acc[8][r];
            }
        }
    }
}

// ---------- CSR build: histogram of dst + within-bucket rank (atomic return value) ----------
__global__ void hist_kernel(const int* __restrict__ ei, int E, int Etot,
                            int* __restrict__ counts, int* __restrict__ rank) {
    int eid = blockIdx.x * 256 + threadIdx.x;
    if (eid >= Etot) return;
    int s, d;
    edge_sd(ei, E, eid, s, d);
    rank[eid] = atomicAdd(&counts[d], 1);
}

// ---------- CSR build: parallel 3-stage exclusive scan ----------
__global__ __launch_bounds__(256) void chunksum_kernel(const int* __restrict__ counts,
                                                       int* __restrict__ csum, int N) {
    __shared__ int red[256];
    int base = blockIdx.x * 1024;
    int s = 0;
    for (int i = threadIdx.x; i < 1024; i += 256) {
        int idx = base + i;
        s += (idx < N) ? counts[idx] : 0;
    }
    red[threadIdx.x] = s;
    __syncthreads();
#pragma unroll
    for (int st = 128; st > 0; st >>= 1) {
        if (threadIdx.x < st) red[threadIdx.x] += red[threadIdx.x + st];
        __syncthreads();
    }
    if (threadIdx.x == 0) csum[blockIdx.x] = red[0];
}

__global__ void chunkscan_kernel(int* __restrict__ csum, int nchunk) {
    int lane = threadIdx.x;
    int v = (lane < nchunk) ? csum[lane] : 0;
    int incl = v;
#pragma unroll
    for (int off = 1; off < 64; off <<= 1) {
        int t = __shfl_up(incl, off);
        if (lane >= off) incl += t;
    }
    if (lane < nchunk) csum[lane] = incl - v;
}

__global__ __launch_bounds__(1024) void scanfinal_kernel(const int* __restrict__ counts,
                                                         const int* __restrict__ csum,
                                                         int* __restrict__ rowptr, int N) {
    __shared__ int wsum[16], woff_s[16];
    int tid = threadIdx.x, lane = tid & 63, wid = tid >> 6;
    int idx = blockIdx.x * 1024 + tid;
    int v = (idx < N) ? counts[idx] : 0;
    int incl = v;
#pragma unroll
    for (int off = 1; off < 64; off <<= 1) {
        int t = __shfl_up(incl, off);
        if (lane >= off) incl += t;
    }
    if (lane == 63) wsum[wid] = incl;
    __syncthreads();
    if (wid == 0 && lane < 16) {
        int w = wsum[lane], iw = w;
#pragma unroll
        for (int off = 1; off < 16; off <<= 1) {
            int t = __shfl_up(iw, off);
            if (lane >= off) iw += t;
        }
        woff_s[lane] = iw - w;
    }
    __syncthreads();
    if (idx < N) rowptr[idx + 1] = csum[blockIdx.x] + woff_s[wid] + incl;
    if (blockIdx.x == 0 && tid == 0) rowptr[0] = 0;
}

// ---------- CSR build: scatter src ids (NO atomics; rank precomputed in hist) ----------
__global__ void scatter_kernel(const int* __restrict__ ei, int E, int Etot,
                               const int* __restrict__ rowptr, const int* __restrict__ rank,
                               unsigned short* __restrict__ ssrc) {
    int eid = blockIdx.x * 256 + threadIdx.x;
    if (eid >= Etot) return;
    int s, d;
    edge_sd(ei, E, eid, s, d);
    ssrc[rowptr[d] + rank[eid]] = (unsigned short)s;
}

// ---------- fused softmax + aggregation: one wave per dst, 8 edges per iteration ----------
template <bool MEAN>
__global__ __launch_bounds__(256) void agg_kernel(const int* __restrict__ rowptr,
                                                  const unsigned short* __restrict__ ssrc,
                                                  const float* __restrict__ a_src,
                                                  const float* __restrict__ a_dst,
                                                  const unsigned short* __restrict__ Hbf,
                                                  float* __restrict__ outbuf, int N) {
    int wid = threadIdx.x >> 6;
    int dst = blockIdx.x * 4 + wid;
    if (dst >= N) return;
    int lane = threadIdx.x & 63;
    int j  = lane >> 3;      // edge slot 0..7 (exp phase)
    int hj = lane & 7;       // head (exp phase)
    int hf = lane >> 3;      // head owning this lane's feature pair (f/16)
    int f  = lane * 2;       // features f, f+1
    int start = rowptr[dst], end = rowptr[dst + 1];
    float adst = a_dst[dst * 8 + hj];

    float acc0 = 0.f, acc1 = 0.f, denl = 0.f;
    for (int base = start; base < end; base += 8) {
        int i = base + j;
        int s = (i < end) ? (int)ssrc[i] : -1;
        float w = 0.f;
        if (s >= 0) w = __expf(lrelu(a_src[s * 8 + hj] + adst));
        denl += w;

        int   sA[8];
        float wA[8];
        unsigned uA[8];
#pragma unroll
        for (int j2 = 0; j2 < 8; j2++) {
            sA[j2] = __shfl(s, j2 * 8);          // uniform lane -> readlane (SGPR)
            wA[j2] = __shfl(w, j2 * 8 + hf);     // per-lane head -> bpermute
        }
#pragma unroll
        for (int j2 = 0; j2 < 8; j2++)
            uA[j2] = (sA[j2] >= 0) ? *(const unsigned*)(Hbf + (size_t)sA[j2] * 128 + f) : 0u;
#pragma unroll
        for (int j2 = 0; j2 < 8; j2++) {
            acc0 += wA[j2] * __uint_as_float(uA[j2] << 16);
            acc1 += wA[j2] * __uint_as_float(uA[j2] & 0xffff0000u);
        }
    }
#pragma unroll
    for (int off = 8; off < 64; off <<= 1) denl += __shfl_xor(denl, off);
    float den = __shfl(denl, hf);
    float inv = 1.f / (den + 1e-16f);
    if (!MEAN) {
        *(float2*)(outbuf + (size_t)dst * 128 + f) = make_float2(acc0 * inv, acc1 * inv);
    } else {
        float r0 = acc0 * inv, r1 = acc1 * inv;
#pragma unroll
        for (int off = 8; off < 64; off <<= 1) {
            r0 += __shfl_xor(r0, off);
            r1 += __shfl_xor(r1, off);
        }
        if (lane < 8)
            *(float2*)(outbuf + (size_t)dst * 16 + lane * 2) =
                make_float2(r0 * 0.125f, r1 * 0.125f);
    }
}

// ---------- batch-norm stats: two-stage deterministic reduction (NO atomics) ----------
template <int C>
__global__ __launch_bounds__(256) void stats_part_kernel(const float* __restrict__ X, int Nrows,
                                                         float* __restrict__ partial,
                                                         int rows_per_block) {
    constexpr int GSZ = 256 / C;
    __shared__ float ls[256], lq[256];
    int c = threadIdx.x % C;
    int g = threadIdx.x / C;
    long base = (long)blockIdx.x * rows_per_block;
    long endr = base + rows_per_block;
    if (endr > Nrows) endr = Nrows;
    float s = 0.f, q = 0.f;
    for (long r = base + g; r < endr; r += GSZ) {
        float v = X[r * C + c];
        s += v;
        q += v * v;
    }
    ls[threadIdx.x] = s;
    lq[threadIdx.x] = q;
    __syncthreads();
#pragma unroll
    for (int st = GSZ / 2; st > 0; st >>= 1) {
        if (g < st) {
            ls[threadIdx.x] += ls[threadIdx.x + st * C];
            lq[threadIdx.x] += lq[threadIdx.x + st * C];
        }
        __syncthreads();
    }
    if (g == 0) {
        partial[(size_t)blockIdx.x * (2 * C) + c] = ls[c];
        partial[(size_t)blockIdx.x * (2 * C) + C + c] = lq[c];
    }
}

template <int C>
__global__ __launch_bounds__(1024) void stats_final_kernel(const float* __restrict__ partial,
                                                           int nblk, float invN,
                                                           float* __restrict__ mu,
                                                           float* __restrict__ rsig) {
    constexpr int G = 1024 / C;
    __shared__ float ls[1024], lq[1024];
    int c = threadIdx.x % C;
    int g = threadIdx.x / C;
    float s = 0.f, q = 0.f;
    for (int b = g; b < nblk; b += G) {
        s += partial[(size_t)b * (2 * C) + c];
        q += partial[(size_t)b * (2 * C) + C + c];
    }
    ls[threadIdx.x] = s;
    lq[threadIdx.x] = q;
    __syncthreads();
#pragma unroll
    for (int st = G / 2; st > 0; st >>= 1) {
        if (g < st) {
            ls[threadIdx.x] += ls[threadIdx.x + st * C];
            lq[threadIdx.x] += lq[threadIdx.x + st * C];
        }
        __syncthreads();
    }
    if (g == 0) {
        float m_ = ls[c] * invN;
        float v = lq[c] * invN - m_ * m_;
        mu[c] = m_;
        rsig[c] = rsqrtf(v + BN_EPS);
    }
}

// ---------- final: BN(16) + logits = v @ Wc + bc ----------
__global__ void final_kernel(const float* __restrict__ out1,
                             const float* __restrict__ mu, const float* __restrict__ rsig,
                             const float* __restrict__ gamma, const float* __restrict__ beta,
                             const float* __restrict__ Wc, const float* __restrict__ bc,
                             float* __restrict__ out, int N) {
    int n = blockIdx.x * 256 + threadIdx.x;
    if (n >= N) return;
    float l0 = bc[0], l1 = bc[1];
#pragma unroll
    for (int c = 0; c < 16; c++) {
        float v = (out1[(size_t)n * 16 + c] - mu[c]) * rsig[c] * gamma[c] + beta[c];
        l0 += v * Wc[c * 2 + 0];
        l1 += v * Wc[c * 2 + 1];
    }
    out[(size_t)n * 2 + 0] = l0;
    out[(size_t)n * 2 + 1] = l1;
}

// ---------- launcher ----------
extern "C" void kernel_launch(void* const* d_in, const int* in_sizes, int n_in,
                              void* d_out, int out_size, void* d_ws, size_t ws_size,
                              hipStream_t stream) {
    const float* x   = (const float*)d_in[0];
    const int*   ei  = (const int*)d_in[1];
    const float* W0  = (const float*)d_in[2];
    const float* as0 = (const float*)d_in[3];
    const float* ad0 = (const float*)d_in[4];
    // d_in[5] = b0: cancelled exactly by the following batch-norm's mean subtraction
    const float* g0  = (const float*)d_in[6];
    const float* be0 = (const float*)d_in[7];
    const float* W1  = (const float*)d_in[8];
    const float* as1 = (const float*)d_in[9];
    const float* ad1 = (const float*)d_in[10];
    // d_in[11] = b1: cancelled by BN as well
    const float* g1  = (const float*)d_in[12];
    const float* be1 = (const float*)d_in[13];
    const float* Wc  = (const float*)d_in[14];
    const float* bc  = (const float*)d_in[15];
    float* out = (float*)d_out;

    int N = in_sizes[0] / 128;
    int E = in_sizes[1] / 2;
    int Etot = E + N;

    // workspace layout
    char* ws = (char*)d_ws;
    size_t off = 0;
    auto walloc = [&](size_t bytes) -> void* {
        void* p = ws + off;
        off += (bytes + 255) & ~(size_t)255;
        return p;
    };
    float*          B       = (float*)walloc((size_t)N * 128 * 4);
    unsigned short* Hbf     = (unsigned short*)walloc((size_t)N * 128 * 2);
    unsigned short* Wt0     = (unsigned short*)walloc(144 * 128 * 2);
    unsigned short* Wt1     = (unsigned short*)walloc(144 * 128 * 2);
    float*          a_src   = (float*)walloc((size_t)N * 8 * 4);
    float*          a_dst   = (float*)walloc((size_t)N * 8 * 4);
    float*          out1    = (float*)walloc((size_t)N * 16 * 4);
    int*            counts  = (int*)walloc((size_t)N * 4);
    int*            rowptr  = (int*)walloc((size_t)(N + 1) * 4);
    int*            rank    = (int*)walloc((size_t)Etot * 4);
    int*            csum    = (int*)walloc(64 * 4);
    unsigned short* ssrc    = (unsigned short*)walloc((size_t)Etot * 2);
    float*          partial = (float*)walloc((size_t)256 * 256 * 4);   // [256 blocks][2*128]
    float*          stats   = (float*)walloc(2 * 128 * 4);
    float* mu = stats, * rsig = stats + 128;

    dim3 b256(256);
    int gE      = (Etot + 255) / 256;
    int gAgg    = (N + 3) / 4;
    int nchunk  = (N + 1023) / 1024;
    const int SBLK = 256;
    const int GEMMBLK = 256;   // persistent blocks; waves grid-stride over row-tiles
    int rpb = (N + SBLK - 1) / SBLK;

    // ---- CSR build (once; same graph for both layers) ----
    hipMemsetAsync(counts, 0, (size_t)N * 4, stream);
    hist_kernel<<<gE, b256, 0, stream>>>(ei, E, Etot, counts, rank);
    chunksum_kernel<<<nchunk, b256, 0, stream>>>(counts, csum, N);
    chunkscan_kernel<<<1, 64, 0, stream>>>(csum, nchunk);
    scanfinal_kernel<<<nchunk, 1024, 0, stream>>>(counts, csum, rowptr, N);
    scatter_kernel<<<gE, b256, 0, stream>>>(ei, E, Etot, rowptr, rank, ssrc);

    // ---- W' build: transpose + bf16 + folded att projections (both layers) ----
    wtrans_kernel<<<144, b256, 0, stream>>>(W0, as0, ad0, W1, as1, ad1, Wt0, Wt1);

    // ---- layer 0 ----
    gemm_att_kernel<<<GEMMBLK, b256, 0, stream>>>(x, Wt0, Hbf, a_src, a_dst,
                                                  nullptr, nullptr, nullptr, nullptr, N);
    agg_kernel<false><<<gAgg, b256, 0, stream>>>(rowptr, ssrc, a_src, a_dst, Hbf, B, N); // B = agg0
    stats_part_kernel<128><<<SBLK, b256, 0, stream>>>(B, N, partial, rpb);
    stats_final_kernel<128><<<1, 1024, 0, stream>>>(partial, SBLK, 1.0f / N, mu, rsig);

    // ---- layer 1 (BN+ELU folded into per-element load path) ----
    gemm_att_kernel<<<GEMMBLK, b256, 0, stream>>>(B, Wt1, Hbf, a_src, a_dst,
                                                  mu, rsig, g0, be0, N);
    agg_kernel<true><<<gAgg, b256, 0, stream>>>(rowptr, ssrc, a_src, a_dst, Hbf, out1, N);
    stats_part_kernel<16><<<SBLK, b256, 0, stream>>>(out1, N, partial, rpb);
    stats_final_kernel<16><<<1, 1024, 0, stream>>>(partial, SBLK, 1.0f / N, mu, rsig);
    final_kernel<<<(N + 255) / 256, b256, 0, stream>>>(out1, mu, rsig, g1, be1, Wc, bc, out, N);
}

// Round 10
// 363.022 us; speedup vs baseline: 1.0962x; 1.0028x over previous
//
#include <hip/hip_runtime.h>
#include <math.h>

#define NEG_SLOPE 0.2f
#define BN_EPS 1e-5f

typedef __attribute__((ext_vector_type(8))) short bf16x8;
typedef __attribute__((ext_vector_type(4))) float f32x4;

// ---------- helpers ----------

__device__ __forceinline__ void edge_sd(const int* __restrict__ ei, int E, int eid, int& s, int& d) {
    if (eid < E) { s = ei[eid]; d = ei[E + eid]; }
    else         { s = d = eid - E; }   // self-loops appended after the E real edges
}

__device__ __forceinline__ float lrelu(float v) { return v > 0.f ? v : NEG_SLOPE * v; }

// round-to-nearest-even fp32 -> bf16 bits
__device__ __forceinline__ unsigned short f2bf(float f) {
    unsigned u = __float_as_uint(f);
    u += 0x7fffu + ((u >> 16) & 1u);
    return (unsigned short)(u >> 16);
}

// ---------- W' pre-pass: Wt = [W | W@att_s | W@att_d] transposed, bf16, tile-major ----------
// Layout: Wt[t*2048 + col16*128 + k], t=0..8. Tile 8: cols 0..7 = a_src proj, 8..15 = a_dst proj.
__global__ void wtrans_kernel(const float* __restrict__ W0, const float* __restrict__ as0,
                              const float* __restrict__ ad0,
                              const float* __restrict__ W1, const float* __restrict__ as1,
                              const float* __restrict__ ad1,
                              unsigned short* __restrict__ Wt0, unsigned short* __restrict__ Wt1) {
    int idx = blockIdx.x * 256 + threadIdx.x;   // 0..36863
    const float *W, *as_, *ad_;
    unsigned short* Wt;
    int i;
    if (idx < 18432) { W = W0; as_ = as0; ad_ = ad0; Wt = Wt0; i = idx; }
    else             { W = W1; as_ = as1; ad_ = ad1; Wt = Wt1; i = idx - 18432; }
    if (i < 16384) {
        int k = i >> 7, n = i & 127;
        Wt[(n >> 4) * 2048 + (n & 15) * 128 + k] = f2bf(W[k * 128 + n]);
    } else {
        int j = i - 16384;          // 0..2047
        int k = j >> 4, hh = j & 15;
        int h = hh & 7;
        const float* av = (hh < 8) ? as_ : ad_;
        float s = 0.f;
#pragma unroll
        for (int c = 0; c < 16; c++) s += W[k * 128 + h * 16 + c] * av[h * 16 + c];
        Wt[8 * 2048 + hh * 128 + k] = f2bf(s);
    }
}

// ---------- persistent-W MFMA GEMM, att logits fused via augmented W' ----------
// W' staged to LDS once per block; waves grid-stride over 16-row tiles with NO
// further barriers. BN+ELU folded into the per-element load path (scale/shift in LDS).
// Launch 1024 blocks: 4 blocks/CU (LDS 39.4KB) x 4 waves = 16 waves/CU.
#define WCOLSTRIDE 132   // ushorts per col (pad 128->132: ds_read_b128 aliasing <=2-way)
#define WTILESZ (16 * WCOLSTRIDE)
__global__ __launch_bounds__(256, 4) void gemm_att_kernel(const float* __restrict__ X,
                                                          const unsigned short* __restrict__ Wt,
                                                          unsigned short* __restrict__ Hbf,
                                                          float* __restrict__ a_src,
                                                          float* __restrict__ a_dst,
                                                          const float* __restrict__ bnmu,
                                                          const float* __restrict__ bnrs,
                                                          const float* __restrict__ gamma,
                                                          const float* __restrict__ beta,
                                                          int Nrows) {
    __shared__ unsigned short wl[9 * WTILESZ];   // 9 col-tiles x 16 cols x 128 k (padded)
    __shared__ float ss[256];                    // scale[128], shift[128]
    int tid = threadIdx.x;

    // fold BN into scale/shift (identity when bnmu == nullptr)
    if (tid < 128) {
        float sc = 1.f, sh = 0.f;
        if (bnmu != nullptr) {
            float rg = bnrs[tid] * gamma[tid];
            sc = rg;
            sh = beta[tid] - bnmu[tid] * rg;
        }
        ss[tid] = sc;
        ss[128 + tid] = sh;
    }
    // stage W' into LDS (once per block)
    for (int i = tid; i < 9 * 16 * 16; i += 256) {   // uint4 chunks of 8 ushorts
        int c = i >> 8, rem = i & 255, col = rem >> 4, k8 = rem & 15;
        uint4 v = *(const uint4*)(Wt + c * 2048 + col * 128 + k8 * 8);
        *(uint4*)(wl + c * WTILESZ + col * WCOLSTRIDE + k8 * 8) = v;
    }
    __syncthreads();

    int w = tid >> 6, lane = tid & 63;
    int m16 = lane & 15;     // A row-in-tile (loads) / B col / C col
    int quad = lane >> 4;    // A,B k-segment (loads) / C row group
    int gw = blockIdx.x * 4 + w;
    int nw = gridDim.x * 4;
    int ntiles = (Nrows + 15) / 16;
    bool dobn = (bnmu != nullptr);
    const float* scp = ss + quad * 8;        // per-ks offset added below (quad segment)
    const float* shp = ss + 128 + quad * 8;

    for (int t = gw; t < ntiles; t += nw) {
        int rl = t * 16 + m16;
        if (rl >= Nrows) rl = Nrows - 1;
        const float* Xr = X + (size_t)rl * 128 + quad * 8;

        // issue all 8 X loads (independent, coalesced: 16 rows x 128B per instr)
        float4 u[8];
#pragma unroll
        for (int ks = 0; ks < 4; ks++) {
            u[2 * ks]     = *(const float4*)(Xr + ks * 32);
            u[2 * ks + 1] = *(const float4*)(Xr + ks * 32 + 4);
        }
        // convert (+BN+ELU for layer 1) -> 4 bf16x8 A-fragments
        bf16x8 afr[4];
#pragma unroll
        for (int ks = 0; ks < 4; ks++) {
            float vv[8] = {u[2 * ks].x, u[2 * ks].y, u[2 * ks].z, u[2 * ks].w,
                           u[2 * ks + 1].x, u[2 * ks + 1].y, u[2 * ks + 1].z, u[2 * ks + 1].w};
            if (dobn) {
#pragma unroll
                for (int j = 0; j < 8; j++) {
                    float tv = vv[j] * scp[ks * 32 + j] + shp[ks * 32 + j];
                    vv[j] = tv > 0.f ? tv : expm1f(tv);
                }
            }
            union { bf16x8 b; unsigned short s[8]; } pk;
#pragma unroll
            for (int j = 0; j < 8; j++) pk.s[j] = f2bf(vv[j]);
            afr[ks] = pk.b;
        }

        // MFMA: 9 col-tiles x 4 k-steps, B from LDS
        f32x4 acc[9];
#pragma unroll
        for (int c = 0; c < 9; c++) acc[c] = (f32x4){0.f, 0.f, 0.f, 0.f};
        const unsigned short* wb = wl + m16 * WCOLSTRIDE + quad * 8;
#pragma unroll
        for (int ks = 0; ks < 4; ks++) {
#pragma unroll
            for (int c = 0; c < 9; c++) {
                bf16x8 b = *(const bf16x8*)(wb + c * WTILESZ + ks * 32);
                acc[c] = __builtin_amdgcn_mfma_f32_16x16x32_bf16(afr[ks], b, acc[c], 0, 0, 0);
            }
        }

        // epilogue: pure stores (C layout: col = m16, row = quad*4 + r)
        int rowb = t * 16 + quad * 4;
#pragma unroll
        for (int c = 0; c < 8; c++) {
#pragma unroll
            for (int r = 0; r < 4; r++) {
                int row = rowb + r;
                if (row < Nrows)
                    Hbf[(size_t)row * 128 + c * 16 + m16] = f2bf(acc[c][r]);
            }
        }
#pragma unroll
        for (int r = 0; r < 4; r++) {
            int row = rowb + r;
            if (row < Nrows) {
                if (m16 < 8) a_src[row * 8 + m16] = acc[8][r];
                else         a_dst[row * 8 + (m16 - 8)] = acc[8][r];
            }
        }
    }
}

// ---------- CSR build: histogram of dst + within-bucket rank (atomic return value) ----------
__global__ void hist_kernel(const int* __restrict__ ei, int E, int Etot,
                            int* __restrict__ counts, int* __restrict__ rank) {
    int eid = blockIdx.x * 256 + threadIdx.x;
    if (eid >= Etot) return;
    int s, d;
    edge_sd(ei, E, eid, s, d);
    rank[eid] = atomicAdd(&counts[d], 1);
}

// ---------- CSR build: parallel 3-stage exclusive scan ----------
__global__ __launch_bounds__(256) void chunksum_kernel(const int* __restrict__ counts,
                                                       int* __restrict__ csum, int N) {
    __shared__ int red[256];
    int base = blockIdx.x * 1024;
    int s = 0;
    for (int i = threadIdx.x; i < 1024; i += 256) {
        int idx = base + i;
        s += (idx < N) ? counts[idx] : 0;
    }
    red[threadIdx.x] = s;
    __syncthreads();
#pragma unroll
    for (int st = 128; st > 0; st >>= 1) {
        if (threadIdx.x < st) red[threadIdx.x] += red[threadIdx.x + st];
        __syncthreads();
    }
    if (threadIdx.x == 0) csum[blockIdx.x] = red[0];
}

__global__ void chunkscan_kernel(int* __restrict__ csum, int nchunk) {
    int lane = threadIdx.x;
    int v = (lane < nchunk) ? csum[lane] : 0;
    int incl = v;
#pragma unroll
    for (int off = 1; off < 64; off <<= 1) {
        int t = __shfl_up(incl, off);
        if (lane >= off) incl += t;
    }
    if (lane < nchunk) csum[lane] = incl - v;
}

__global__ __launch_bounds__(1024) void scanfinal_kernel(const int* __restrict__ counts,
                                                         const int* __restrict__ csum,
                                                         int* __restrict__ rowptr, int N) {
    __shared__ int wsum[16], woff_s[16];
    int tid = threadIdx.x, lane = tid & 63, wid = tid >> 6;
    int idx = blockIdx.x * 1024 + tid;
    int v = (idx < N) ? counts[idx] : 0;
    int incl = v;
#pragma unroll
    for (int off = 1; off < 64; off <<= 1) {
        int t = __shfl_up(incl, off);
        if (lane >= off) incl += t;
    }
    if (lane == 63) wsum[wid] = incl;
    __syncthreads();
    if (wid == 0 && lane < 16) {
        int w = wsum[lane], iw = w;
#pragma unroll
        for (int off = 1; off < 16; off <<= 1) {
            int t = __shfl_up(iw, off);
            if (lane >= off) iw += t;
        }
        woff_s[lane] = iw - w;
    }
    __syncthreads();
    if (idx < N) rowptr[idx + 1] = csum[blockIdx.x] + woff_s[wid] + incl;
    if (blockIdx.x == 0 && tid == 0) rowptr[0] = 0;
}

// ---------- CSR build: scatter src ids (NO atomics; rank precomputed in hist) ----------
__global__ void scatter_kernel(const int* __restrict__ ei, int E, int Etot,
                               const int* __restrict__ rowptr, const int* __restrict__ rank,
                               unsigned short* __restrict__ ssrc) {
    int eid = blockIdx.x * 256 + threadIdx.x;
    if (eid >= Etot) return;
    int s, d;
    edge_sd(ei, E, eid, s, d);
    ssrc[rowptr[d] + rank[eid]] = (unsigned short)s;
}

// ---------- fused softmax + aggregation: one wave per dst, 8 edges per iteration ----------
template <bool MEAN>
__global__ __launch_bounds__(256) void agg_kernel(const int* __restrict__ rowptr,
                                                  const unsigned short* __restrict__ ssrc,
                                                  const float* __restrict__ a_src,
                                                  const float* __restrict__ a_dst,
                                                  const unsigned short* __restrict__ Hbf,
                                                  float* __restrict__ outbuf, int N) {
    int wid = threadIdx.x >> 6;
    int dst = blockIdx.x * 4 + wid;
    if (dst >= N) return;
    int lane = threadIdx.x & 63;
    int j  = lane >> 3;      // edge slot 0..7 (exp phase)
    int hj = lane & 7;       // head (exp phase)
    int hf = lane >> 3;      // head owning this lane's feature pair (f/16)
    int f  = lane * 2;       // features f, f+1
    int start = rowptr[dst], end = rowptr[dst + 1];
    float adst = a_dst[dst * 8 + hj];

    float acc0 = 0.f, acc1 = 0.f, denl = 0.f;
    for (int base = start; base < end; base += 8) {
        int i = base + j;
        int s = (i < end) ? (int)ssrc[i] : -1;
        float w = 0.f;
        if (s >= 0) w = __expf(lrelu(a_src[s * 8 + hj] + adst));
        denl += w;

        int   sA[8];
        float wA[8];
        unsigned uA[8];
#pragma unroll
        for (int j2 = 0; j2 < 8; j2++) {
            sA[j2] = __shfl(s, j2 * 8);          // uniform lane -> readlane (SGPR)
            wA[j2] = __shfl(w, j2 * 8 + hf);     // per-lane head -> bpermute
        }
#pragma unroll
        for (int j2 = 0; j2 < 8; j2++)
            uA[j2] = (sA[j2] >= 0) ? *(const unsigned*)(Hbf + (size_t)sA[j2] * 128 + f) : 0u;
#pragma unroll
        for (int j2 = 0; j2 < 8; j2++) {
            acc0 += wA[j2] * __uint_as_float(uA[j2] << 16);
            acc1 += wA[j2] * __uint_as_float(uA[j2] & 0xffff0000u);
        }
    }
#pragma unroll
    for (int off = 8; off < 64; off <<= 1) denl += __shfl_xor(denl, off);
    float den = __shfl(denl, hf);
    float inv = 1.f / (den + 1e-16f);
    if (!MEAN) {
        *(float2*)(outbuf + (size_t)dst * 128 + f) = make_float2(acc0 * inv, acc1 * inv);
    } else {
        float r0 = acc0 * inv, r1 = acc1 * inv;
#pragma unroll
        for (int off = 8; off < 64; off <<= 1) {
            r0 += __shfl_xor(r0, off);
            r1 += __shfl_xor(r1, off);
        }
        if (lane < 8)
            *(float2*)(outbuf + (size_t)dst * 16 + lane * 2) =
                make_float2(r0 * 0.125f, r1 * 0.125f);
    }
}

// ---------- batch-norm stats: two-stage deterministic reduction (NO atomics) ----------
template <int C>
__global__ __launch_bounds__(256) void stats_part_kernel(const float* __restrict__ X, int Nrows,
                                                         float* __restrict__ partial,
                                                         int rows_per_block) {
    constexpr int GSZ = 256 / C;
    __shared__ float ls[256], lq[256];
    int c = threadIdx.x % C;
    int g = threadIdx.x / C;
    long base = (long)blockIdx.x * rows_per_block;
    long endr = base + rows_per_block;
    if (endr > Nrows) endr = Nrows;
    float s = 0.f, q = 0.f;
    for (long r = base + g; r < endr; r += GSZ) {
        float v = X[r * C + c];
        s += v;
        q += v * v;
    }
    ls[threadIdx.x] = s;
    lq[threadIdx.x] = q;
    __syncthreads();
#pragma unroll
    for (int st = GSZ / 2; st > 0; st >>= 1) {
        if (g < st) {
            ls[threadIdx.x] += ls[threadIdx.x + st * C];
            lq[threadIdx.x] += lq[threadIdx.x + st * C];
        }
        __syncthreads();
    }
    if (g == 0) {
        partial[(size_t)blockIdx.x * (2 * C) + c] = ls[c];
        partial[(size_t)blockIdx.x * (2 * C) + C + c] = lq[c];
    }
}

template <int C>
__global__ __launch_bounds__(1024) void stats_final_kernel(const float* __restrict__ partial,
                                                           int nblk, float invN,
                                                           float* __restrict__ mu,
                                                           float* __restrict__ rsig) {
    constexpr int G = 1024 / C;
    __shared__ float ls[1024], lq[1024];
    int c = threadIdx.x % C;
    int g = threadIdx.x / C;
    float s = 0.f, q = 0.f;
    for (int b = g; b < nblk; b += G) {
        s += partial[(size_t)b * (2 * C) + c];
        q += partial[(size_t)b * (2 * C) + C + c];
    }
    ls[threadIdx.x] = s;
    lq[threadIdx.x] = q;
    __syncthreads();
#pragma unroll
    for (int st = G / 2; st > 0; st >>= 1) {
        if (g < st) {
            ls[threadIdx.x] += ls[threadIdx.x + st * C];
            lq[threadIdx.x] += lq[threadIdx.x + st * C];
        }
        __syncthreads();
    }
    if (g == 0) {
        float m_ = ls[c] * invN;
        float v = lq[c] * invN - m_ * m_;
        mu[c] = m_;
        rsig[c] = rsqrtf(v + BN_EPS);
    }
}

// ---------- final: BN(16) + logits = v @ Wc + bc ----------
__global__ void final_kernel(const float* __restrict__ out1,
                             const float* __restrict__ mu, const float* __restrict__ rsig,
                             const float* __restrict__ gamma, const float* __restrict__ beta,
                             const float* __restrict__ Wc, const float* __restrict__ bc,
                             float* __restrict__ out, int N) {
    int n = blockIdx.x * 256 + threadIdx.x;
    if (n >= N) return;
    float l0 = bc[0], l1 = bc[1];
#pragma unroll
    for (int c = 0; c < 16; c++) {
        float v = (out1[(size_t)n * 16 + c] - mu[c]) * rsig[c] * gamma[c] + beta[c];
        l0 += v * Wc[c * 2 + 0];
        l1 += v * Wc[c * 2 + 1];
    }
    out[(size_t)n * 2 + 0] = l0;
    out[(size_t)n * 2 + 1] = l1;
}

// ---------- launcher ----------
extern "C" void kernel_launch(void* const* d_in, const int* in_sizes, int n_in,
                              void* d_out, int out_size, void* d_ws, size_t ws_size,
                              hipStream_t stream) {
    const float* x   = (const float*)d_in[0];
    const int*   ei  = (const int*)d_in[1];
    const float* W0  = (const float*)d_in[2];
    const float* as0 = (const float*)d_in[3];
    const float* ad0 = (const float*)d_in[4];
    // d_in[5] = b0: cancelled exactly by the following batch-norm's mean subtraction
    const float* g0  = (const float*)d_in[6];
    const float* be0 = (const float*)d_in[7];
    const float* W1  = (const float*)d_in[8];
    const float* as1 = (const float*)d_in[9];
    const float* ad1 = (const float*)d_in[10];
    // d_in[11] = b1: cancelled by BN as well
    const float* g1  = (const float*)d_in[12];
    const float* be1 = (const float*)d_in[13];
    const float* Wc  = (const float*)d_in[14];
    const float* bc  = (const float*)d_in[15];
    float* out = (float*)d_out;

    int N = in_sizes[0] / 128;
    int E = in_sizes[1] / 2;
    int Etot = E + N;

    // workspace layout
    char* ws = (char*)d_ws;
    size_t off = 0;
    auto walloc = [&](size_t bytes) -> void* {
        void* p = ws + off;
        off += (bytes + 255) & ~(size_t)255;
        return p;
    };
    float*          B       = (float*)walloc((size_t)N * 128 * 4);
    unsigned short* Hbf     = (unsigned short*)walloc((size_t)N * 128 * 2);
    unsigned short* Wt0     = (unsigned short*)walloc(144 * 128 * 2);
    unsigned short* Wt1     = (unsigned short*)walloc(144 * 128 * 2);
    float*          a_src   = (float*)walloc((size_t)N * 8 * 4);
    float*          a_dst   = (float*)walloc((size_t)N * 8 * 4);
    float*          out1    = (float*)walloc((size_t)N * 16 * 4);
    int*            counts  = (int*)walloc((size_t)N * 4);
    int*            rowptr  = (int*)walloc((size_t)(N + 1) * 4);
    int*            rank    = (int*)walloc((size_t)Etot * 4);
    int*            csum    = (int*)walloc(64 * 4);
    unsigned short* ssrc    = (unsigned short*)walloc((size_t)Etot * 2);
    float*          partial = (float*)walloc((size_t)256 * 256 * 4);   // [256 blocks][2*128]
    float*          stats   = (float*)walloc(2 * 128 * 4);
    float* mu = stats, * rsig = stats + 128;

    dim3 b256(256);
    int gE      = (Etot + 255) / 256;
    int gAgg    = (N + 3) / 4;
    int nchunk  = (N + 1023) / 1024;
    const int SBLK = 256;
    const int GEMMBLK = 1024;   // 4 blocks/CU (39.4KB LDS) x 4 waves = 16 waves/CU
    int rpb = (N + SBLK - 1) / SBLK;

    // ---- CSR build (once; same graph for both layers) ----
    hipMemsetAsync(counts, 0, (size_t)N * 4, stream);
    hist_kernel<<<gE, b256, 0, stream>>>(ei, E, Etot, counts, rank);
    chunksum_kernel<<<nchunk, b256, 0, stream>>>(counts, csum, N);
    chunkscan_kernel<<<1, 64, 0, stream>>>(csum, nchunk);
    scanfinal_kernel<<<nchunk, 1024, 0, stream>>>(counts, csum, rowptr, N);
    scatter_kernel<<<gE, b256, 0, stream>>>(ei, E, Etot, rowptr, rank, ssrc);

    // ---- W' build: transpose + bf16 + folded att projections (both layers) ----
    wtrans_kernel<<<144, b256, 0, stream>>>(W0, as0, ad0, W1, as1, ad1, Wt0, Wt1);

    // ---- layer 0 ----
    gemm_att_kernel<<<GEMMBLK, b256, 0, stream>>>(x, Wt0, Hbf, a_src, a_dst,
                                                  nullptr, nullptr, nullptr, nullptr, N);
    agg_kernel<false><<<gAgg, b256, 0, stream>>>(rowptr, ssrc, a_src, a_dst, Hbf, B, N); // B = agg0
    stats_part_kernel<128><<<SBLK, b256, 0, stream>>>(B, N, partial, rpb);
    stats_final_kernel<128><<<1, 1024, 0, stream>>>(partial, SBLK, 1.0f / N, mu, rsig);

    // ---- layer 1 (BN+ELU folded into per-element load path) ----
    gemm_att_kernel<<<GEMMBLK, b256, 0, stream>>>(B, Wt1, Hbf, a_src, a_dst,
                                                  mu, rsig, g0, be0, N);
    agg_kernel<true><<<gAgg, b256, 0, stream>>>(rowptr, ssrc, a_src, a_dst, Hbf, out1, N);
    stats_part_kernel<16><<<SBLK, b256, 0, stream>>>(out1, N, partial, rpb);
    stats_final_kernel<16><<<1, 1024, 0, stream>>>(partial, SBLK, 1.0f / N, mu, rsig);
    final_kernel<<<(N + 255) / 256, b256, 0, stream>>>(out1, mu, rsig, g1, be1, Wc, bc, out, N);
}

// Round 11
// 361.145 us; speedup vs baseline: 1.1019x; 1.0052x over previous
//
#include <hip/hip_runtime.h>
#include <math.h>

#define NEG_SLOPE 0.2f
#define BN_EPS 1e-5f

typedef __attribute__((ext_vector_type(8))) short bf16x8;
typedef __attribute__((ext_vector_type(4))) float f32x4;
typedef __attribute__((ext_vector_type(8))) unsigned short us8;

// ---------- helpers ----------

__device__ __forceinline__ void edge_sd(const int* __restrict__ ei, int E, int eid, int& s, int& d) {
    if (eid < E) { s = ei[eid]; d = ei[E + eid]; }
    else         { s = d = eid - E; }   // self-loops appended after the E real edges
}

__device__ __forceinline__ float lrelu(float v) { return v > 0.f ? v : NEG_SLOPE * v; }

// round-to-nearest-even fp32 -> bf16 bits
__device__ __forceinline__ unsigned short f2bf(float f) {
    unsigned u = __float_as_uint(f);
    u += 0x7fffu + ((u >> 16) & 1u);
    return (unsigned short)(u >> 16);
}

// ---------- W' pre-pass: Wt = [W | W@att_s | W@att_d] transposed, bf16, tile-major ----------
// COLUMN-PERMUTED tiles: actual col n lives in tile c = n&7 at position p = n>>3.
// => lane m16's 8 accumulators (c=0..7) are 8 CONSECUTIVE output cols m16*8+c,
//    so the GEMM epilogue packs them into one 16-B store (kills write amplification).
// Tile 8 (att): cols 0..7 = a_src proj, 8..15 = a_dst proj (position = hh, unpermuted).
__global__ void wtrans_kernel(const float* __restrict__ W0, const float* __restrict__ as0,
                              const float* __restrict__ ad0,
                              const float* __restrict__ W1, const float* __restrict__ as1,
                              const float* __restrict__ ad1,
                              unsigned short* __restrict__ Wt0, unsigned short* __restrict__ Wt1) {
    int idx = blockIdx.x * 256 + threadIdx.x;   // 0..36863
    const float *W, *as_, *ad_;
    unsigned short* Wt;
    int i;
    if (idx < 18432) { W = W0; as_ = as0; ad_ = ad0; Wt = Wt0; i = idx; }
    else             { W = W1; as_ = as1; ad_ = ad1; Wt = Wt1; i = idx - 18432; }
    if (i < 16384) {
        int k = i >> 7, n = i & 127;
        Wt[(n & 7) * 2048 + (n >> 3) * 128 + k] = f2bf(W[k * 128 + n]);
    } else {
        int j = i - 16384;          // 0..2047
        int k = j >> 4, hh = j & 15;
        int h = hh & 7;
        const float* av = (hh < 8) ? as_ : ad_;
        float s = 0.f;
#pragma unroll
        for (int c = 0; c < 16; c++) s += W[k * 128 + h * 16 + c] * av[h * 16 + c];
        Wt[8 * 2048 + hh * 128 + k] = f2bf(s);
    }
}

// ---------- persistent-W MFMA GEMM, att logits fused via augmented W' ----------
// W' staged to LDS once per block; waves grid-stride over 16-row tiles with NO
// further barriers. BN+ELU folded into the per-element load path (scale/shift in LDS).
// Epilogue: 4 coalesced 16-B stores per tile (column-permuted tiles).
#define WCOLSTRIDE 132   // ushorts per col (pad 128->132: ds_read_b128 aliasing <=2-way)
#define WTILESZ (16 * WCOLSTRIDE)
__global__ __launch_bounds__(256, 4) void gemm_att_kernel(const float* __restrict__ X,
                                                          const unsigned short* __restrict__ Wt,
                                                          unsigned short* __restrict__ Hbf,
                                                          float* __restrict__ a_src,
                                                          float* __restrict__ a_dst,
                                                          const float* __restrict__ bnmu,
                                                          const float* __restrict__ bnrs,
                                                          const float* __restrict__ gamma,
                                                          const float* __restrict__ beta,
                                                          int Nrows) {
    __shared__ unsigned short wl[9 * WTILESZ];   // 9 col-tiles x 16 positions x 128 k (padded)
    __shared__ float ss[256];                    // scale[128], shift[128]
    int tid = threadIdx.x;

    // fold BN into scale/shift (identity when bnmu == nullptr)
    if (tid < 128) {
        float sc = 1.f, sh = 0.f;
        if (bnmu != nullptr) {
            float rg = bnrs[tid] * gamma[tid];
            sc = rg;
            sh = beta[tid] - bnmu[tid] * rg;
        }
        ss[tid] = sc;
        ss[128 + tid] = sh;
    }
    // stage W' into LDS (once per block)
    for (int i = tid; i < 9 * 16 * 16; i += 256) {   // uint4 chunks of 8 ushorts
        int c = i >> 8, rem = i & 255, col = rem >> 4, k8 = rem & 15;
        uint4 v = *(const uint4*)(Wt + c * 2048 + col * 128 + k8 * 8);
        *(uint4*)(wl + c * WTILESZ + col * WCOLSTRIDE + k8 * 8) = v;
    }
    __syncthreads();

    int w = tid >> 6, lane = tid & 63;
    int m16 = lane & 15;     // A row-in-tile (loads) / B position / C position
    int quad = lane >> 4;    // A,B k-segment (loads) / C row group
    int gw = blockIdx.x * 4 + w;
    int nw = gridDim.x * 4;
    int ntiles = (Nrows + 15) / 16;
    bool dobn = (bnmu != nullptr);
    const float* scp = ss + quad * 8;        // per-ks offset added below (quad segment)
    const float* shp = ss + 128 + quad * 8;

    for (int t = gw; t < ntiles; t += nw) {
        int rl = t * 16 + m16;
        if (rl >= Nrows) rl = Nrows - 1;
        const float* Xr = X + (size_t)rl * 128 + quad * 8;

        // issue all 8 X loads (independent, coalesced: 16 rows x 128B per instr)
        float4 u[8];
#pragma unroll
        for (int ks = 0; ks < 4; ks++) {
            u[2 * ks]     = *(const float4*)(Xr + ks * 32);
            u[2 * ks + 1] = *(const float4*)(Xr + ks * 32 + 4);
        }
        // convert (+BN+ELU for layer 1) -> 4 bf16x8 A-fragments
        bf16x8 afr[4];
#pragma unroll
        for (int ks = 0; ks < 4; ks++) {
            float vv[8] = {u[2 * ks].x, u[2 * ks].y, u[2 * ks].z, u[2 * ks].w,
                           u[2 * ks + 1].x, u[2 * ks + 1].y, u[2 * ks + 1].z, u[2 * ks + 1].w};
            if (dobn) {
#pragma unroll
                for (int j = 0; j < 8; j++) {
                    float tv = vv[j] * scp[ks * 32 + j] + shp[ks * 32 + j];
                    vv[j] = tv > 0.f ? tv : expm1f(tv);
                }
            }
            union { bf16x8 b; unsigned short s[8]; } pk;
#pragma unroll
            for (int j = 0; j < 8; j++) pk.s[j] = f2bf(vv[j]);
            afr[ks] = pk.b;
        }

        // MFMA: 9 col-tiles x 4 k-steps, B from LDS
        f32x4 acc[9];
#pragma unroll
        for (int c = 0; c < 9; c++) acc[c] = (f32x4){0.f, 0.f, 0.f, 0.f};
        const unsigned short* wb = wl + m16 * WCOLSTRIDE + quad * 8;
#pragma unroll
        for (int ks = 0; ks < 4; ks++) {
#pragma unroll
            for (int c = 0; c < 9; c++) {
                bf16x8 b = *(const bf16x8*)(wb + c * WTILESZ + ks * 32);
                acc[c] = __builtin_amdgcn_mfma_f32_16x16x32_bf16(afr[ks], b, acc[c], 0, 0, 0);
            }
        }

        // epilogue: lane's cols c=0..7 are consecutive (m16*8+c) -> one us8 store per row
        int rowb = t * 16 + quad * 4;
#pragma unroll
        for (int r = 0; r < 4; r++) {
            int row = rowb + r;
            if (row < Nrows) {
                us8 pk;
#pragma unroll
                for (int c = 0; c < 8; c++) pk[c] = f2bf(acc[c][r]);
                *(us8*)(Hbf + (size_t)row * 128 + m16 * 8) = pk;
                if (m16 < 8) a_src[row * 8 + m16] = acc[8][r];
                else         a_dst[row * 8 + (m16 - 8)] = acc[8][r];
            }
        }
    }
}

// ---------- CSR build: histogram of dst + within-bucket rank (atomic return value) ----------
__global__ void hist_kernel(const int* __restrict__ ei, int E, int Etot,
                            int* __restrict__ counts, int* __restrict__ rank) {
    int eid = blockIdx.x * 256 + threadIdx.x;
    if (eid >= Etot) return;
    int s, d;
    edge_sd(ei, E, eid, s, d);
    rank[eid] = atomicAdd(&counts[d], 1);
}

// ---------- CSR build: parallel 3-stage exclusive scan ----------
__global__ __launch_bounds__(256) void chunksum_kernel(const int* __restrict__ counts,
                                                       int* __restrict__ csum, int N) {
    __shared__ int red[256];
    int base = blockIdx.x * 1024;
    int s = 0;
    for (int i = threadIdx.x; i < 1024; i += 256) {
        int idx = base + i;
        s += (idx < N) ? counts[idx] : 0;
    }
    red[threadIdx.x] = s;
    __syncthreads();
#pragma unroll
    for (int st = 128; st > 0; st >>= 1) {
        if (threadIdx.x < st) red[threadIdx.x] += red[threadIdx.x + st];
        __syncthreads();
    }
    if (threadIdx.x == 0) csum[blockIdx.x] = red[0];
}

__global__ void chunkscan_kernel(int* __restrict__ csum, int nchunk) {
    int lane = threadIdx.x;
    int v = (lane < nchunk) ? csum[lane] : 0;
    int incl = v;
#pragma unroll
    for (int off = 1; off < 64; off <<= 1) {
        int t = __shfl_up(incl, off);
        if (lane >= off) incl += t;
    }
    if (lane < nchunk) csum[lane] = incl - v;
}

__global__ __launch_bounds__(1024) void scanfinal_kernel(const int* __restrict__ counts,
                                                         const int* __restrict__ csum,
                                                         int* __restrict__ rowptr, int N) {
    __shared__ int wsum[16], woff_s[16];
    int tid = threadIdx.x, lane = tid & 63, wid = tid >> 6;
    int idx = blockIdx.x * 1024 + tid;
    int v = (idx < N) ? counts[idx] : 0;
    int incl = v;
#pragma unroll
    for (int off = 1; off < 64; off <<= 1) {
        int t = __shfl_up(incl, off);
        if (lane >= off) incl += t;
    }
    if (lane == 63) wsum[wid] = incl;
    __syncthreads();
    if (wid == 0 && lane < 16) {
        int w = wsum[lane], iw = w;
#pragma unroll
        for (int off = 1; off < 16; off <<= 1) {
            int t = __shfl_up(iw, off);
            if (lane >= off) iw += t;
        }
        woff_s[lane] = iw - w;
    }
    __syncthreads();
    if (idx < N) rowptr[idx + 1] = csum[blockIdx.x] + woff_s[wid] + incl;
    if (blockIdx.x == 0 && tid == 0) rowptr[0] = 0;
}

// ---------- CSR build: scatter src ids (NO atomics; rank precomputed in hist) ----------
__global__ void scatter_kernel(const int* __restrict__ ei, int E, int Etot,
                               const int* __restrict__ rowptr, const int* __restrict__ rank,
                               unsigned short* __restrict__ ssrc) {
    int eid = blockIdx.x * 256 + threadIdx.x;
    if (eid >= Etot) return;
    int s, d;
    edge_sd(ei, E, eid, s, d);
    ssrc[rowptr[d] + rank[eid]] = (unsigned short)s;
}

// ---------- fused softmax + aggregation: one wave per dst, 8 edges per iteration ----------
template <bool MEAN>
__global__ __launch_bounds__(256) void agg_kernel(const int* __restrict__ rowptr,
                                                  const unsigned short* __restrict__ ssrc,
                                                  const float* __restrict__ a_src,
                                                  const float* __restrict__ a_dst,
                                                  const unsigned short* __restrict__ Hbf,
                                                  float* __restrict__ outbuf, int N) {
    int wid = threadIdx.x >> 6;
    int dst = blockIdx.x * 4 + wid;
    if (dst >= N) return;
    int lane = threadIdx.x & 63;
    int j  = lane >> 3;      // edge slot 0..7 (exp phase)
    int hj = lane & 7;       // head (exp phase)
    int hf = lane >> 3;      // head owning this lane's feature pair (f/16)
    int f  = lane * 2;       // features f, f+1
    int start = rowptr[dst], end = rowptr[dst + 1];
    float adst = a_dst[dst * 8 + hj];

    float acc0 = 0.f, acc1 = 0.f, denl = 0.f;
    for (int base = start; base < end; base += 8) {
        int i = base + j;
        int s = (i < end) ? (int)ssrc[i] : -1;
        float w = 0.f;
        if (s >= 0) w = __expf(lrelu(a_src[s * 8 + hj] + adst));
        denl += w;

        int   sA[8];
        float wA[8];
        unsigned uA[8];
#pragma unroll
        for (int j2 = 0; j2 < 8; j2++) {
            sA[j2] = __shfl(s, j2 * 8);          // uniform lane -> readlane (SGPR)
            wA[j2] = __shfl(w, j2 * 8 + hf);     // per-lane head -> bpermute
        }
#pragma unroll
        for (int j2 = 0; j2 < 8; j2++)
            uA[j2] = (sA[j2] >= 0) ? *(const unsigned*)(Hbf + (size_t)sA[j2] * 128 + f) : 0u;
#pragma unroll
        for (int j2 = 0; j2 < 8; j2++) {
            acc0 += wA[j2] * __uint_as_float(uA[j2] << 16);
            acc1 += wA[j2] * __uint_as_float(uA[j2] & 0xffff0000u);
        }
    }
#pragma unroll
    for (int off = 8; off < 64; off <<= 1) denl += __shfl_xor(denl, off);
    float den = __shfl(denl, hf);
    float inv = 1.f / (den + 1e-16f);
    if (!MEAN) {
        *(float2*)(outbuf + (size_t)dst * 128 + f) = make_float2(acc0 * inv, acc1 * inv);
    } else {
        float r0 = acc0 * inv, r1 = acc1 * inv;
#pragma unroll
        for (int off = 8; off < 64; off <<= 1) {
            r0 += __shfl_xor(r0, off);
            r1 += __shfl_xor(r1, off);
        }
        if (lane < 8)
            *(float2*)(outbuf + (size_t)dst * 16 + lane * 2) =
                make_float2(r0 * 0.125f, r1 * 0.125f);
    }
}

// ---------- batch-norm stats: two-stage deterministic reduction (NO atomics) ----------
template <int C>
__global__ __launch_bounds__(256) void stats_part_kernel(const float* __restrict__ X, int Nrows,
                                                         float* __restrict__ partial,
                                                         int rows_per_block) {
    constexpr int GSZ = 256 / C;
    __shared__ float ls[256], lq[256];
    int c = threadIdx.x % C;
    int g = threadIdx.x / C;
    long base = (long)blockIdx.x * rows_per_block;
    long endr = base + rows_per_block;
    if (endr > Nrows) endr = Nrows;
    float s = 0.f, q = 0.f;
    for (long r = base + g; r < endr; r += GSZ) {
        float v = X[r * C + c];
        s += v;
        q += v * v;
    }
    ls[threadIdx.x] = s;
    lq[threadIdx.x] = q;
    __syncthreads();
#pragma unroll
    for (int st = GSZ / 2; st > 0; st >>= 1) {
        if (g < st) {
            ls[threadIdx.x] += ls[threadIdx.x + st * C];
            lq[threadIdx.x] += lq[threadIdx.x + st * C];
        }
        __syncthreads();
    }
    if (g == 0) {
        partial[(size_t)blockIdx.x * (2 * C) + c] = ls[c];
        partial[(size_t)blockIdx.x * (2 * C) + C + c] = lq[c];
    }
}

template <int C>
__global__ __launch_bounds__(1024) void stats_final_kernel(const float* __restrict__ partial,
                                                           int nblk, float invN,
                                                           float* __restrict__ mu,
                                                           float* __restrict__ rsig) {
    constexpr int G = 1024 / C;
    __shared__ float ls[1024], lq[1024];
    int c = threadIdx.x % C;
    int g = threadIdx.x / C;
    float s = 0.f, q = 0.f;
    for (int b = g; b < nblk; b += G) {
        s += partial[(size_t)b * (2 * C) + c];
        q += partial[(size_t)b * (2 * C) + C + c];
    }
    ls[threadIdx.x] = s;
    lq[threadIdx.x] = q;
    __syncthreads();
#pragma unroll
    for (int st = G / 2; st > 0; st >>= 1) {
        if (g < st) {
            ls[threadIdx.x] += ls[threadIdx.x + st * C];
            lq[threadIdx.x] += lq[threadIdx.x + st * C];
        }
        __syncthreads();
    }
    if (g == 0) {
        float m_ = ls[c] * invN;
        float v = lq[c] * invN - m_ * m_;
        mu[c] = m_;
        rsig[c] = rsqrtf(v + BN_EPS);
    }
}

// ---------- final: BN(16) + logits = v @ Wc + bc ----------
__global__ void final_kernel(const float* __restrict__ out1,
                             const float* __restrict__ mu, const float* __restrict__ rsig,
                             const float* __restrict__ gamma, const float* __restrict__ beta,
                             const float* __restrict__ Wc, const float* __restrict__ bc,
                             float* __restrict__ out, int N) {
    int n = blockIdx.x * 256 + threadIdx.x;
    if (n >= N) return;
    float l0 = bc[0], l1 = bc[1];
#pragma unroll
    for (int c = 0; c < 16; c++) {
        float v = (out1[(size_t)n * 16 + c] - mu[c]) * rsig[c] * gamma[c] + beta[c];
        l0 += v * Wc[c * 2 + 0];
        l1 += v * Wc[c * 2 + 1];
    }
    out[(size_t)n * 2 + 0] = l0;
    out[(size_t)n * 2 + 1] = l1;
}

// ---------- launcher ----------
extern "C" void kernel_launch(void* const* d_in, const int* in_sizes, int n_in,
                              void* d_out, int out_size, void* d_ws, size_t ws_size,
                              hipStream_t stream) {
    const float* x   = (const float*)d_in[0];
    const int*   ei  = (const int*)d_in[1];
    const float* W0  = (const float*)d_in[2];
    const float* as0 = (const float*)d_in[3];
    const float* ad0 = (const float*)d_in[4];
    // d_in[5] = b0: cancelled exactly by the following batch-norm's mean subtraction
    const float* g0  = (const float*)d_in[6];
    const float* be0 = (const float*)d_in[7];
    const float* W1  = (const float*)d_in[8];
    const float* as1 = (const float*)d_in[9];
    const float* ad1 = (const float*)d_in[10];
    // d_in[11] = b1: cancelled by BN as well
    const float* g1  = (const float*)d_in[12];
    const float* be1 = (const float*)d_in[13];
    const float* Wc  = (const float*)d_in[14];
    const float* bc  = (const float*)d_in[15];
    float* out = (float*)d_out;

    int N = in_sizes[0] / 128;
    int E = in_sizes[1] / 2;
    int Etot = E + N;

    // workspace layout
    char* ws = (char*)d_ws;
    size_t off = 0;
    auto walloc = [&](size_t bytes) -> void* {
        void* p = ws + off;
        off += (bytes + 255) & ~(size_t)255;
        return p;
    };
    float*          B       = (float*)walloc((size_t)N * 128 * 4);
    unsigned short* Hbf     = (unsigned short*)walloc((size_t)N * 128 * 2);
    unsigned short* Wt0     = (unsigned short*)walloc(144 * 128 * 2);
    unsigned short* Wt1     = (unsigned short*)walloc(144 * 128 * 2);
    float*          a_src   = (float*)walloc((size_t)N * 8 * 4);
    float*          a_dst   = (float*)walloc((size_t)N * 8 * 4);
    float*          out1    = (float*)walloc((size_t)N * 16 * 4);
    int*            counts  = (int*)walloc((size_t)N * 4);
    int*            rowptr  = (int*)walloc((size_t)(N + 1) * 4);
    int*            rank    = (int*)walloc((size_t)Etot * 4);
    int*            csum    = (int*)walloc(64 * 4);
    unsigned short* ssrc    = (unsigned short*)walloc((size_t)Etot * 2);
    float*          partial = (float*)walloc((size_t)256 * 256 * 4);   // [256 blocks][2*128]
    float*          stats   = (float*)walloc(2 * 128 * 4);
    float* mu = stats, * rsig = stats + 128;

    dim3 b256(256);
    int gE      = (Etot + 255) / 256;
    int gAgg    = (N + 3) / 4;
    int nchunk  = (N + 1023) / 1024;
    const int SBLK = 256;
    const int GEMMBLK = 1024;   // 4 blocks/CU (39.4KB LDS) x 4 waves = 16 waves/CU
    int rpb = (N + SBLK - 1) / SBLK;

    // ---- CSR build (once; same graph for both layers) ----
    hipMemsetAsync(counts, 0, (size_t)N * 4, stream);
    hist_kernel<<<gE, b256, 0, stream>>>(ei, E, Etot, counts, rank);
    chunksum_kernel<<<nchunk, b256, 0, stream>>>(counts, csum, N);
    chunkscan_kernel<<<1, 64, 0, stream>>>(csum, nchunk);
    scanfinal_kernel<<<nchunk, 1024, 0, stream>>>(counts, csum, rowptr, N);
    scatter_kernel<<<gE, b256, 0, stream>>>(ei, E, Etot, rowptr, rank, ssrc);

    // ---- W' build: transpose + bf16 + folded att projections (both layers) ----
    wtrans_kernel<<<144, b256, 0, stream>>>(W0, as0, ad0, W1, as1, ad1, Wt0, Wt1);

    // ---- layer 0 ----
    gemm_att_kernel<<<GEMMBLK, b256, 0, stream>>>(x, Wt0, Hbf, a_src, a_dst,
                                                  nullptr, nullptr, nullptr, nullptr, N);
    agg_kernel<false><<<gAgg, b256, 0, stream>>>(rowptr, ssrc, a_src, a_dst, Hbf, B, N); // B = agg0
    stats_part_kernel<128><<<SBLK, b256, 0, stream>>>(B, N, partial, rpb);
    stats_final_kernel<128><<<1, 1024, 0, stream>>>(partial, SBLK, 1.0f / N, mu, rsig);

    // ---- layer 1 (BN+ELU folded into per-element load path) ----
    gemm_att_kernel<<<GEMMBLK, b256, 0, stream>>>(B, Wt1, Hbf, a_src, a_dst,
                                                  mu, rsig, g0, be0, N);
    agg_kernel<true><<<gAgg, b256, 0, stream>>>(rowptr, ssrc, a_src, a_dst, Hbf, out1, N);
    stats_part_kernel<16><<<SBLK, b256, 0, stream>>>(out1, N, partial, rpb);
    stats_final_kernel<16><<<1, 1024, 0, stream>>>(partial, SBLK, 1.0f / N, mu, rsig);
    final_kernel<<<(N + 255) / 256, b256, 0, stream>>>(out1, mu, rsig, g1, be1, Wc, bc, out, N);
}